// Round 11
// baseline (423.438 us; speedup 1.0000x reference)
//
#include <hip/hip_runtime.h>
#include <hip/hip_fp16.h>
#include <math.h>

namespace {

constexpr int NN = 4096;
constexpr int EE = 131072;
constexpr int E2 = EE + NN;      // 135168 pool edges (orig + self loops)
constexpr int HH = 128;
constexpr int KC = 3277;         // ceil(0.8*4096)
constexpr int UP = 3584;         // U row stride (8*448)
constexpr int A2P = 3328;        // A2 row/col padded dim

typedef _Float16 f16x8 __attribute__((ext_vector_type(8)));
typedef _Float16 f16x4 __attribute__((ext_vector_type(4)));
typedef float f32x4 __attribute__((ext_vector_type(4)));

constexpr int A2B_RT = (KC + 3) / 4;   // 820 row-groups (4 waves x 1 row)
constexpr int KQ = A2P / 4;             // 832 K-quarter for k_mm
constexpr int PCAP = 32;                // k_pool LDS row-cache capacity

__device__ __forceinline__ float lrelu02(float x){ return x > 0.f ? x : 0.2f * x; }

__device__ __forceinline__ float redSum128(float* red, int t, float v){
  red[t] = v; __syncthreads();
  #pragma unroll
  for (int s = 64; s > 0; s >>= 1){ if (t < s) red[t] += red[t + s]; __syncthreads(); }
  float r = red[0]; __syncthreads();
  return r;
}
__device__ __forceinline__ float redMax128(float* red, int t, float v){
  red[t] = v; __syncthreads();
  #pragma unroll
  for (int s = 64; s > 0; s >>= 1){ if (t < s) red[t] = fmaxf(red[t], red[t + s]); __syncthreads(); }
  float r = red[0]; __syncthreads();
  return r;
}

__global__ void k_zero_init(int* cntD, int* cntS, int* deg, float* out){
  int i = blockIdx.x * blockDim.x + threadIdx.x;
  if (i < NN){ cntD[i] = 0; cntS[i] = 0; }
  if (i < KC) deg[i] = 0;
  if (i < 512) out[i] = 0.f;
}

__global__ void k_count(const int* __restrict__ ei, int* cntD, int* cntS){
  int e = blockIdx.x * blockDim.x + threadIdx.x;
  if (e >= E2) return;
  int u, v;
  if (e < EE){ u = ei[e]; v = ei[EE + e]; } else { u = e - EE; v = u; }
  atomicAdd(&cntD[v], 1);
  atomicAdd(&cntS[u], 1);
}

__global__ void k_scan(const int* cntD, const int* cntS, int* rowD, int* rowS, int* curD, int* curS){
  __shared__ int sc[1024];
  int t = threadIdx.x;
  for (int pass = 0; pass < 2; ++pass){
    const int* cnt = pass ? cntS : cntD;
    int* row = pass ? rowS : rowD;
    int* cur = pass ? curS : curD;
    int c0 = cnt[t*4+0], c1 = cnt[t*4+1], c2 = cnt[t*4+2], c3 = cnt[t*4+3];
    int tot = c0 + c1 + c2 + c3;
    sc[t] = tot; __syncthreads();
    for (int offs = 1; offs < 1024; offs <<= 1){
      int v = (t >= offs) ? sc[t - offs] : 0;
      __syncthreads();
      sc[t] += v;
      __syncthreads();
    }
    int excl = sc[t] - tot;
    int r0 = excl, r1 = r0 + c0, r2 = r1 + c1, r3 = r2 + c2;
    row[t*4+0] = r0; row[t*4+1] = r1; row[t*4+2] = r2; row[t*4+3] = r3;
    cur[t*4+0] = r0; cur[t*4+1] = r1; cur[t*4+2] = r2; cur[t*4+3] = r3;
    if (t == 1023) row[NN] = r3 + c3;
    __syncthreads();
  }
}

__global__ void k_scatter(const int* __restrict__ ei, int* curD, int* curS,
                          int* colD, int* dstS, int* mapSD){
  int e = blockIdx.x * blockDim.x + threadIdx.x;
  if (e >= E2) return;
  int u, v;
  if (e < EE){ u = ei[e]; v = ei[EE + e]; } else { u = e - EE; v = u; }
  int p = atomicAdd(&curD[v], 1); colD[p] = u;
  int q = atomicAdd(&curS[u], 1); dstS[q] = v; mapSD[q] = p;
}

// fused GraphConv: edge-mean gather + linear + relu + column-mean.
// 512 threads, 16 nodes/block; 4 gather groups of 128 threads.
__global__ void k_eml(const float* __restrict__ xin, const int* __restrict__ rowD,
                      const int* __restrict__ colD,
                      const float* __restrict__ Wrel, const float* __restrict__ brel,
                      const float* __restrict__ Wroot, float* __restrict__ xout, int rows,
                      float* __restrict__ cmout){
  __shared__ float ms[16][HH];
  __shared__ float xs[16][HH];
  __shared__ float cmred[512];
  int tid = threadIdx.x;
  int r0 = blockIdx.x * 16;
  int sub = tid >> 7;        // 0..3
  int t = tid & 127;
  for (int l = tid; l < 16*HH; l += 512){
    int r = l >> 7, c = l & 127; int gr = r0 + r;
    xs[r][c] = (gr < rows) ? xin[(size_t)gr*HH + c] : 0.f;
  }
  for (int rr = 0; rr < 4; ++rr){
    int r = rr*4 + sub;
    int v = r0 + r;
    float acc = 0.f, dg = 0.f;
    if (v < rows){
      int beg = rowD[v], end = rowD[v+1];
      int p = beg;
      for (; p + 8 <= end; p += 8){
        int u0 = colD[p],   u1 = colD[p+1], u2 = colD[p+2], u3 = colD[p+3];
        int u4 = colD[p+4], u5 = colD[p+5], u6 = colD[p+6], u7 = colD[p+7];
        float a0 = xin[(size_t)u0*HH + t];
        float a1 = xin[(size_t)u1*HH + t];
        float a2 = xin[(size_t)u2*HH + t];
        float a3 = xin[(size_t)u3*HH + t];
        float a4 = xin[(size_t)u4*HH + t];
        float a5 = xin[(size_t)u5*HH + t];
        float a6 = xin[(size_t)u6*HH + t];
        float a7 = xin[(size_t)u7*HH + t];
        if (u0 != v) acc += a0;
        if (u1 != v) acc += a1;
        if (u2 != v) acc += a2;
        if (u3 != v) acc += a3;
        if (u4 != v) acc += a4;
        if (u5 != v) acc += a5;
        if (u6 != v) acc += a6;
        if (u7 != v) acc += a7;
      }
      for (; p < end; ++p){ int u = colD[p]; if (u != v) acc += xin[(size_t)u*HH + t]; }
      dg = (float)(end - beg - 1);
    }
    ms[r][t] = acc / fmaxf(dg, 1.f);
  }
  __syncthreads();
  int h = t, hgrp = sub;
  float acc4[4] = {0.f,0.f,0.f,0.f};
  for (int c = 0; c < HH; ++c){
    float wr = Wrel[h*HH + c], wo = Wroot[h*HH + c];
    #pragma unroll
    for (int r = 0; r < 4; ++r) acc4[r] += ms[hgrp*4 + r][c]*wr + xs[hgrp*4 + r][c]*wo;
  }
  float bb = brel[h];
  float csum = 0.f;
  #pragma unroll
  for (int r = 0; r < 4; ++r){
    int gr = r0 + hgrp*4 + r;
    if (gr < rows){
      float val = fmaxf(acc4[r] + bb, 0.f);
      xout[(size_t)gr*HH + h] = val;
      csum += val;
    }
  }
  cmred[tid] = csum; __syncthreads();
  if (tid < 128)
    atomicAdd(&cmout[h], (cmred[tid] + cmred[tid+128] + cmred[tid+256] + cmred[tid+384]) / (float)rows);
}

// dense-conv linear: mean from 4 K-quarter partials / deg; optional xout; fused column-mean.
__global__ void k_lin2(const float* __restrict__ part, const int* __restrict__ deg,
                       const float* __restrict__ xin,
                       const float* __restrict__ Wrel, const float* __restrict__ brel,
                       const float* __restrict__ Wroot, float* __restrict__ xout, int rows,
                       float* __restrict__ cmout){
  __shared__ float ms[16][HH];
  __shared__ float xs[16][HH];
  __shared__ float cmred[256];
  const float* p0 = part;
  const float* p1 = part + (size_t)KC*HH;
  const float* p2 = part + (size_t)2*KC*HH;
  const float* p3 = part + (size_t)3*KC*HH;
  int tid = threadIdx.x;
  int r0 = blockIdx.x * 16;
  for (int l = tid; l < 16*HH; l += 256){
    int r = l >> 7, c = l & 127; int gr = r0 + r;
    float mv = 0.f, xv = 0.f;
    if (gr < rows){
      size_t idx = (size_t)gr*HH + c;
      float d = fmaxf((float)deg[gr], 1.f);
      mv = ((p0[idx] + p1[idx]) + (p2[idx] + p3[idx])) / d;
      xv = xin[idx];
    }
    ms[r][c] = mv; xs[r][c] = xv;
  }
  __syncthreads();
  int h = tid & 127, hgrp = tid >> 7;
  float acc[8] = {0.f,0.f,0.f,0.f,0.f,0.f,0.f,0.f};
  for (int c = 0; c < HH; ++c){
    float wr = Wrel[h*HH + c], wo = Wroot[h*HH + c];
    #pragma unroll
    for (int r = 0; r < 8; ++r) acc[r] += ms[hgrp*8 + r][c]*wr + xs[hgrp*8 + r][c]*wo;
  }
  float bb = brel[h];
  float csum = 0.f;
  #pragma unroll
  for (int r = 0; r < 8; ++r){
    int gr = r0 + hgrp*8 + r;
    if (gr < rows){
      float val = fmaxf(acc[r] + bb, 0.f);
      if (xout) xout[(size_t)gr*HH + h] = val;
      csum += val;
    }
  }
  cmred[tid] = csum; __syncthreads();
  if (tid < 128) atomicAdd(&cmout[h], (cmred[tid] + cmred[tid + 128]) / (float)rows);
}

// wA2[c] = sum_h wattA[h]*Wlin[h,c];  wA2[HH] = sum_h blin[h]*wattA[h]
__global__ void k_wprep(const float* __restrict__ Wlin, const float* __restrict__ blin,
                        const float* __restrict__ Watt, float* __restrict__ wA2){
  int c = threadIdx.x;
  float s = 0.f;
  for (int hh = 0; hh < HH; ++hh) s += Watt[hh] * Wlin[hh*HH + c];
  wA2[c] = s;
  if (c == 0){
    float q = 0.f;
    for (int hh = 0; hh < HH; ++hh) q += blin[hh] * Watt[hh];
    wA2[HH] = q;
  }
}

__global__ void k_xdot(const float* __restrict__ x2, const float* __restrict__ Watt, float* __restrict__ xdot){
  __shared__ float red[128];
  int n = blockIdx.x, t = threadIdx.x;
  float v = redSum128(red, t, x2[(size_t)n*HH + t] * Watt[HH + t]);
  if (t == 0) xdot[n] = v;
}

// per dst node v: xq max -> qdot; edge-softmax stats; x_new; wD; fused LEConv partials.
// First PCAP neighbor rows cached in LDS (f16) during max phase; weighted phase reuses.
__global__ void k_pool(const float* __restrict__ x2, const int* __restrict__ rowD, const int* __restrict__ colD,
                       const float* __restrict__ xdotA, const float* __restrict__ wA2, const float* __restrict__ battp,
                       const float* __restrict__ W1, const float* __restrict__ b1,
                       const float* __restrict__ W2, const float* __restrict__ W3, const float* __restrict__ b3,
                       float* qdotA, float* mA, float* sA, float* __restrict__ xnew, float* __restrict__ wD,
                       float* aA, float* bA, float* cA){
  __shared__ float red[128];
  __shared__ float wmem[128];
  __shared__ int uc[128];
  __shared__ __half xc[PCAP][HH];   // 8 KB
  int v = blockIdx.x, t = threadIdx.x;
  int beg = rowD[v], end = rowD[v+1];
  float batt = battp[0];
  float mx = -3.402823466e38f;
  int p = beg;
  for (; p + 4 <= end; p += 4){
    float a0 = x2[(size_t)colD[p]*HH + t];
    float a1 = x2[(size_t)colD[p+1]*HH + t];
    float a2 = x2[(size_t)colD[p+2]*HH + t];
    float a3 = x2[(size_t)colD[p+3]*HH + t];
    int o = p - beg;
    if (o + 4 <= PCAP){
      xc[o][t] = __float2half(a0); xc[o+1][t] = __float2half(a1);
      xc[o+2][t] = __float2half(a2); xc[o+3][t] = __float2half(a3);
    } else if (o < PCAP){
      xc[o][t] = __float2half(a0);
      if (o+1 < PCAP) xc[o+1][t] = __float2half(a1);
      if (o+2 < PCAP) xc[o+2][t] = __float2half(a2);
    }
    mx = fmaxf(fmaxf(fmaxf(fmaxf(mx, a0), a1), a2), a3);
  }
  for (; p < end; ++p){
    float a = x2[(size_t)colD[p]*HH + t];
    int o = p - beg;
    if (o < PCAP) xc[o][t] = __float2half(a);
    mx = fmaxf(mx, a);
  }
  float qd = redSum128(red, t, mx * wA2[t]) + wA2[HH];
  float lm = -3.402823466e38f;
  for (p = beg + t; p < end; p += 128) lm = fmaxf(lm, lrelu02(qd + xdotA[colD[p]] + batt));
  float mm = redMax128(red, t, lm);
  float ls = 0.f;
  for (p = beg + t; p < end; p += 128) ls += expf(lrelu02(qd + xdotA[colD[p]] + batt) - mm);
  float ss = redSum128(red, t, ls);
  float acc = 0.f;
  for (int basep = beg; basep < end; basep += 128){
    int cnt = min(128, end - basep);
    if (t < cnt){
      int u = colD[basep + t];
      uc[t] = u;
      float w = expf(lrelu02(qd + xdotA[u] + batt) - mm) / ss;
      wmem[t] = w;
      wD[basep + t] = w;
    }
    __syncthreads();
    int ob = basep - beg;
    int i = 0;
    for (; i + 4 <= cnt; i += 4){
      int o = ob + i;
      float a0, a1, a2, a3;
      if (o + 4 <= PCAP){
        a0 = __half2float(xc[o][t]);   a1 = __half2float(xc[o+1][t]);
        a2 = __half2float(xc[o+2][t]); a3 = __half2float(xc[o+3][t]);
      } else {
        a0 = (o   < PCAP) ? __half2float(xc[o][t])   : x2[(size_t)uc[i]*HH + t];
        a1 = (o+1 < PCAP) ? __half2float(xc[o+1][t]) : x2[(size_t)uc[i+1]*HH + t];
        a2 = (o+2 < PCAP) ? __half2float(xc[o+2][t]) : x2[(size_t)uc[i+2]*HH + t];
        a3 = (o+3 < PCAP) ? __half2float(xc[o+3][t]) : x2[(size_t)uc[i+3]*HH + t];
      }
      acc += wmem[i]*a0 + wmem[i+1]*a1 + wmem[i+2]*a2 + wmem[i+3]*a3;
    }
    for (; i < cnt; ++i){
      int o = ob + i;
      float a = (o < PCAP) ? __half2float(xc[o][t]) : x2[(size_t)uc[i]*HH + t];
      acc += wmem[i] * a;
    }
    __syncthreads();
  }
  xnew[(size_t)v*HH + t] = acc;
  float s1 = redSum128(red, t, acc * W1[t]);
  float s2 = redSum128(red, t, acc * W2[t]);
  float s3 = redSum128(red, t, acc * W3[t]);
  if (t == 0){
    qdotA[v] = qd; mA[v] = mm; sA[v] = ss;
    aA[v] = s1 + b1[0]; bA[v] = s2; cA[v] = s3 + b3[0];
  }
}

__global__ void k_fit(const int* __restrict__ rowD, const int* __restrict__ colD,
                      const float* __restrict__ aA, const float* __restrict__ bA, const float* __restrict__ cA,
                      float* __restrict__ fitA){
  __shared__ float red[128];
  int v = blockIdx.x, t = threadIdx.x;
  int beg = rowD[v], end = rowD[v+1];
  float la = 0.f;
  for (int p = beg + t; p < end; p += 128) la += aA[colD[p]];
  float s = redSum128(red, t, la);
  if (t == 0){
    float g = s - (float)(end - beg) * bA[v] + cA[v];
    fitA[v] = 1.f / (1.f + expf(-g));
  }
}

// Exact top-K SET selection via radix-select (1 block, 1024 threads).
__global__ void k_sel(const float* __restrict__ fitA, int* perm, float* fitk, int* kcol){
  __shared__ unsigned keys[NN];
  __shared__ int hist[256];
  __shared__ int sc[1024];
  __shared__ int bc[2];
  int t = threadIdx.x;
  #pragma unroll
  for (int r = 0; r < 4; ++r){
    int i = t + r*1024;
    unsigned b = __float_as_uint(fitA[i]);
    keys[i] = (b & 0x80000000u) ? ~b : (b ^ 0x80000000u);
  }
  __syncthreads();
  unsigned prefix = 0;
  int kneed = KC;
  #pragma unroll
  for (int round = 0; round < 4; ++round){
    int shift = 24 - round*8;
    unsigned pmask = (round == 0) ? 0u : (0xFFFFFFFFu << (shift + 8));
    if (t < 256) hist[t] = 0;
    __syncthreads();
    #pragma unroll
    for (int r = 0; r < 4; ++r){
      unsigned kv = keys[t + r*1024];
      if ((kv & pmask) == prefix)
        atomicAdd(&hist[(kv >> shift) & 0xFF], 1);
    }
    __syncthreads();
    if (t == 0){
      int acc = 0, chosen = 0, rem = kneed;
      for (int bkt = 255; bkt >= 0; --bkt){
        int c = hist[bkt];
        if (acc + c >= kneed){ chosen = bkt; rem = kneed - acc; break; }
        acc += c;
      }
      bc[0] = chosen; bc[1] = rem;
    }
    __syncthreads();
    prefix |= ((unsigned)bc[0]) << shift;
    kneed = bc[1];
    __syncthreads();
  }
  unsigned T = prefix;
  int need_eq = kneed;
  int cnt[4]; int tot = 0;
  #pragma unroll
  for (int r = 0; r < 4; ++r){
    unsigned kv = keys[t*4 + r];
    int g = (kv > T) ? 1 : 0;
    int e = (kv == T) ? 1 : 0;
    cnt[r] = (g << 16) | e;
    tot += cnt[r];
  }
  sc[t] = tot; __syncthreads();
  for (int offs = 1; offs < 1024; offs <<= 1){
    int v = (t >= offs) ? sc[t - offs] : 0;
    __syncthreads();
    sc[t] += v;
    __syncthreads();
  }
  int gtot = sc[1023] >> 16;
  int run = sc[t] - tot;
  #pragma unroll
  for (int r = 0; r < 4; ++r){
    int i = t*4 + r;
    int g = cnt[r] >> 16, e = cnt[r] & 0xFFFF;
    int gpos = run >> 16, epos = run & 0xFFFF;
    int pos = -1;
    if (g) pos = gpos;
    else if (e && epos < need_eq) pos = gtot + epos;
    if (pos >= 0){ perm[pos] = i; fitk[pos] = fitA[i]; kcol[i] = pos; }
    else kcol[i] = -1;
    run += cnt[r];
  }
}

// fused: xp[j,:] = xnew[perm[j],:]*fitk[j]  AND  Xt[h][j] = f16(xp[j][h])
__global__ void k_xpt(const float* __restrict__ xnew, const int* __restrict__ perm,
                      const float* __restrict__ fitk, float* __restrict__ xp,
                      __half* __restrict__ Xt){
  __shared__ float T2[64][129];
  int t = threadIdx.x;
  int j0 = blockIdx.x * 64;
  for (int l = t; l < 64*32; l += 256){
    int jl = l >> 5, hg = (l & 31) * 4;
    int j = j0 + jl;
    float4 v = make_float4(0.f, 0.f, 0.f, 0.f);
    if (j < KC){
      float f = fitk[j];
      const float* src = xnew + (size_t)perm[j]*HH + hg;
      v.x = src[0]*f; v.y = src[1]*f; v.z = src[2]*f; v.w = src[3]*f;
      *(float4*)(xp + (size_t)j*HH + hg) = v;
    }
    T2[jl][hg] = v.x; T2[jl][hg+1] = v.y; T2[jl][hg+2] = v.z; T2[jl][hg+3] = v.w;
  }
  __syncthreads();
  for (int idx = t; idx < 128*64; idx += 256){
    int h = idx >> 6, jl = idx & 63;
    Xt[(size_t)h*A2P + j0 + jl] = __float2half(T2[jl][h]);
  }
}

// src-ordered packed (kcol, w) for k_U; dst-ordered byte-offset + f16 weight for k_A2B
__global__ void k_wS(const int* __restrict__ mapSD, const int* __restrict__ dstS,
                     const int* __restrict__ kcol, const float* __restrict__ wD,
                     const int* __restrict__ colD,
                     int2* __restrict__ kwS, unsigned* __restrict__ offsD,
                     __half* __restrict__ wHD){
  int q = blockIdx.x * blockDim.x + threadIdx.x;
  if (q >= E2) return;
  float w = wD[mapSD[q]];
  int k = kcol[dstS[q]];
  kwS[q] = make_int2(k, __float_as_int(w));
  offsD[q] = (unsigned)colD[q] * (UP*2);
  wHD[q] = __float2half(wD[q]);
}

// U[n,:] = (A @ S)[n,:]  (dense f16 row, stride UP, zero-padded)
__global__ void k_U(const int* __restrict__ rowS, const int* __restrict__ dstS,
                    const int2* __restrict__ kwS, __half* __restrict__ U){
  __shared__ float acc[UP];   // 14 KB
  int t = threadIdx.x, n = blockIdx.x;
  for (int i = t; i < UP; i += 256) acc[i] = 0.f;
  __syncthreads();
  int b = rowS[n], e = rowS[n+1];
  for (int p = b; p < e; ++p){
    int j = dstS[p];
    int b2 = rowS[j], e2 = rowS[j+1];
    for (int q = b2 + t; q < e2; q += 256){
      int2 kw = kwS[q];
      if (kw.x >= 0) atomicAdd(&acc[kw.x], __int_as_float(kw.y));
    }
  }
  __syncthreads();
  __half2* Ur = (__half2*)(U + (size_t)n * UP);
  for (int i = t; i < UP/2; i += 256)
    Ur[i] = __halves2half2(__float2half(acc[2*i]), __float2half(acc[2*i+1]));
}

// A2 row k1 (per wave, R9 single-row 8-deep) -> written TRANSPOSED into A2T via LDS stage.
// 8 col-chunks of 448 (XCD-pinned); fused nonzero count -> deg.
__global__ void k_A2B(const int* __restrict__ rowD,
                      const unsigned* __restrict__ offsD, const __half* __restrict__ wHDh,
                      const int* __restrict__ perm,
                      const __half* __restrict__ Uh, __half* __restrict__ A2T,
                      int* __restrict__ deg){
  __shared__ _Float16 st[4][456];
  int cc = blockIdx.x & 7;
  int rt = blockIdx.x >> 3;
  int t = threadIdx.x;
  int w = t >> 6, lane = t & 63;
  int k1 = rt*4 + w;
  bool act = lane < 56;
  unsigned laneoff = (unsigned)(cc*448*2 + lane*16);
  const char* Ub = (const char*)Uh;
  const _Float16* wHD = (const _Float16*)wHDh;

  f16x8 accA = (f16x8)(_Float16)0, accB = (f16x8)(_Float16)0;
  f16x8 accC = (f16x8)(_Float16)0, accD = (f16x8)(_Float16)0;

  if (k1 < KC){
    int v1 = perm[k1];
    int p = rowD[v1], end = rowD[v1+1];
    int pre = (8 - (p & 7)) & 7;
    if (pre > end - p) pre = end - p;
    for (int z = 0; z < pre; ++z, ++p){
      unsigned off = offsD[p];
      _Float16 w0 = wHD[p];
      if (act){
        f16x8 u = *(const f16x8*)(Ub + (size_t)(off + laneoff));
        accA += u * w0;
      }
    }
    for (; p + 8 <= end; p += 8){
      uint4 oA = *(const uint4*)(offsD + p);
      uint4 oB = *(const uint4*)(offsD + p + 4);
      f16x8 wv = *(const f16x8*)(wHD + p);
      if (act){
        f16x8 u0 = *(const f16x8*)(Ub + (size_t)(oA.x + laneoff));
        f16x8 u1 = *(const f16x8*)(Ub + (size_t)(oA.y + laneoff));
        f16x8 u2 = *(const f16x8*)(Ub + (size_t)(oA.z + laneoff));
        f16x8 u3 = *(const f16x8*)(Ub + (size_t)(oA.w + laneoff));
        f16x8 u4 = *(const f16x8*)(Ub + (size_t)(oB.x + laneoff));
        f16x8 u5 = *(const f16x8*)(Ub + (size_t)(oB.y + laneoff));
        f16x8 u6 = *(const f16x8*)(Ub + (size_t)(oB.z + laneoff));
        f16x8 u7 = *(const f16x8*)(Ub + (size_t)(oB.w + laneoff));
        accA += u0 * wv[0];
        accB += u1 * wv[1];
        accC += u2 * wv[2];
        accD += u3 * wv[3];
        accA += u4 * wv[4];
        accB += u5 * wv[5];
        accC += u6 * wv[6];
        accD += u7 * wv[7];
      }
    }
    for (; p < end; ++p){
      unsigned off = offsD[p];
      _Float16 w0 = wHD[p];
      if (act){
        f16x8 u = *(const f16x8*)(Ub + (size_t)(off + laneoff));
        accB += u * w0;
      }
    }
  }
  f16x8 acc = (accA + accB) + (accC + accD);

  int col0 = cc*448 + lane * 8;
  f16x8 o = (f16x8)(_Float16)0;
  int c = 0;
  if (act && k1 < KC){
    #pragma unroll
    for (int e = 0; e < 8; ++e){
      int col = col0 + e;
      _Float16 hv = (col == k1 || col >= KC) ? (_Float16)0 : acc[e];
      o[e] = hv;
      c += (hv != (_Float16)0) ? 1 : 0;
    }
  }
  #pragma unroll
  for (int s = 32; s > 0; s >>= 1) c += __shfl_down(c, s);
  if (lane == 0 && k1 < KC) atomicAdd(&deg[k1], c);

  if (act) *(f16x8*)&st[w][lane*8] = o;
  __syncthreads();
  for (int tau = t; tau < 448; tau += 256){
    int i = cc*448 + tau;       // A2T row
    if (i >= A2P) continue;
    f16x4 val;
    val[0] = st[0][tau]; val[1] = st[1][tau]; val[2] = st[2][tau]; val[3] = st[3][tau];
    *(f16x4*)(A2T + (size_t)i*A2P + rt*4) = val;
  }
}

// zero A2T[:, KC..A2P) pad columns (K-dim tail must be 0 for k_mm)
__global__ void k_ztail(__half* __restrict__ A2T){
  constexpr int NJ = A2P - KC;   // 51
  int idx = blockIdx.x * 256 + threadIdx.x;
  if (idx >= A2P * NJ) return;
  int i = idx / NJ, j = KC + idx % NJ;
  A2T[(size_t)i*A2P + j] = __float2half(0.f);
}

// Xt[h][j] = (f16) X[j][h], zero-padded for j >= KC.
__global__ void k_xt(const float* __restrict__ X, __half* __restrict__ Xt){
  __shared__ float T2[64][129];
  int t = threadIdx.x;
  int j0 = blockIdx.x * 64;
  for (int l = t; l < 64*32; l += 256){
    int jl = l >> 5, hg = (l & 31) * 4;
    int j = j0 + jl;
    float4 v = make_float4(0.f, 0.f, 0.f, 0.f);
    if (j < KC) v = *(const float4*)(X + (size_t)j*HH + hg);
    T2[jl][hg] = v.x; T2[jl][hg+1] = v.y; T2[jl][hg+2] = v.z; T2[jl][hg+3] = v.w;
  }
  __syncthreads();
  for (int idx = t; idx < 128*64; idx += 256){
    int h = idx >> 6, jl = idx & 63;
    Xt[(size_t)h*A2P + j0 + jl] = __float2half(T2[jl][h]);
  }
}

// MFMA dagg: 32i x 128h per block, K-split 4, atomic-free.
__global__ void k_mm(const __half* __restrict__ A2Th, const __half* __restrict__ Xth,
                     float* __restrict__ part){
  const _Float16* A2T = (const _Float16*)A2Th;
  const _Float16* Xt  = (const _Float16*)Xth;
  int t = threadIdx.x;
  int lane = t & 63, w = t >> 6;
  int i0 = (blockIdx.x >> 2) * 32;
  int kq = blockIdx.x & 3;
  int kbeg = kq * KQ;
  float* po = part + (size_t)kq * KC * HH;
  int l15 = lane & 15, lk = (lane >> 4) * 8;
  const _Float16* Ar0 = A2T + (size_t)(i0 + l15) * A2P + lk + kbeg;
  const _Float16* Ar1 = Ar0 + (size_t)16 * A2P;
  const _Float16* B0 = Xt + (size_t)(w*32 + l15) * A2P + lk + kbeg;
  const _Float16* B1 = B0 + (size_t)16 * A2P;
  f32x4 acc00 = (f32x4)0.f, acc01 = (f32x4)0.f;
  f32x4 acc10 = (f32x4)0.f, acc11 = (f32x4)0.f;
  for (int kk = 0; kk < KQ; kk += 64){
    f16x8 a00 = *(const f16x8*)(Ar0 + kk);
    f16x8 a01 = *(const f16x8*)(Ar0 + kk + 32);
    f16x8 a10 = *(const f16x8*)(Ar1 + kk);
    f16x8 a11 = *(const f16x8*)(Ar1 + kk + 32);
    f16x8 b00 = *(const f16x8*)(B0 + kk);
    f16x8 b01 = *(const f16x8*)(B1 + kk);
    f16x8 b10 = *(const f16x8*)(B0 + kk + 32);
    f16x8 b11 = *(const f16x8*)(B1 + kk + 32);
    acc00 = __builtin_amdgcn_mfma_f32_16x16x32_f16(a00, b00, acc00, 0, 0, 0);
    acc01 = __builtin_amdgcn_mfma_f32_16x16x32_f16(a00, b01, acc01, 0, 0, 0);
    acc10 = __builtin_amdgcn_mfma_f32_16x16x32_f16(a10, b00, acc10, 0, 0, 0);
    acc11 = __builtin_amdgcn_mfma_f32_16x16x32_f16(a10, b01, acc11, 0, 0, 0);
    acc00 = __builtin_amdgcn_mfma_f32_16x16x32_f16(a01, b10, acc00, 0, 0, 0);
    acc01 = __builtin_amdgcn_mfma_f32_16x16x32_f16(a01, b11, acc01, 0, 0, 0);
    acc10 = __builtin_amdgcn_mfma_f32_16x16x32_f16(a11, b10, acc10, 0, 0, 0);
    acc11 = __builtin_amdgcn_mfma_f32_16x16x32_f16(a11, b11, acc11, 0, 0, 0);
  }
  int rbase = (lane >> 4) * 4;
  #pragma unroll
  for (int r = 0; r < 4; ++r){
    int ia = i0 + rbase + r;
    int ib = ia + 16;
    if (ia < KC){
      po[(size_t)ia*HH + w*32 + l15] = acc00[r];
      po[(size_t)ia*HH + w*32 + 16 + l15] = acc01[r];
    }
    if (ib < KC){
      po[(size_t)ib*HH + w*32 + l15] = acc10[r];
      po[(size_t)ib*HH + w*32 + 16 + l15] = acc11[r];
    }
  }
}

} // namespace

extern "C" void kernel_launch(void* const* d_in, const int* in_sizes, int n_in,
                              void* d_out, int out_size, void* d_ws, size_t ws_size,
                              hipStream_t stream){
  (void)in_sizes; (void)n_in; (void)out_size; (void)ws_size;
  const float* x      = (const float*)d_in[0];
  const int*   ei     = (const int*)d_in[1];
  const float* c0Wrel = (const float*)d_in[2];
  const float* c0brel = (const float*)d_in[3];
  const float* c0Wroot= (const float*)d_in[4];
  const float* c1Wrel = (const float*)d_in[5];
  const float* c1brel = (const float*)d_in[6];
  const float* c1Wroot= (const float*)d_in[7];
  const float* c2Wrel = (const float*)d_in[8];
  const float* c2brel = (const float*)d_in[9];
  const float* c2Wroot= (const float*)d_in[10];
  const float* c3Wrel = (const float*)d_in[11];
  const float* c3brel = (const float*)d_in[12];
  const float* c3Wroot= (const float*)d_in[13];
  const float* Wlin   = (const float*)d_in[14];
  const float* blin   = (const float*)d_in[15];
  const float* Watt   = (const float*)d_in[16];
  const float* batt   = (const float*)d_in[17];
  const float* W1     = (const float*)d_in[18];
  const float* b1     = (const float*)d_in[19];
  const float* W2     = (const float*)d_in[20];
  const float* W3     = (const float*)d_in[21];
  const float* b3     = (const float*)d_in[22];
  float* out = (float*)d_out;

  char* base = (char*)d_ws;
  size_t off = 0;
  auto carve = [&](size_t bytes) -> void* {
    void* p = base + off;
    off += (bytes + 255) & ~(size_t)255;
    return p;
  };
  float* x1    = (float*)carve((size_t)NN*HH*4);
  float* x2b   = (float*)carve((size_t)NN*HH*4);
  float* xnew  = (float*)carve((size_t)NN*HH*4);
  float* xp    = (float*)carve((size_t)KC*HH*4);
  float* x3    = (float*)carve((size_t)KC*HH*4);
  float* part  = (float*)carve((size_t)4*KC*HH*4);    // 4 K-quarter partials
  __half* A2T  = (__half*)carve((size_t)A2P*A2P*2);   // ~22.2 MB (dedicated; no aliasing)
  __half* U    = (__half*)carve((size_t)NN*UP*2);     // ~29.4 MB
  __half* Xt   = (__half*)carve((size_t)HH*A2P*2);
  float* xdot  = (float*)carve(NN*4);
  float* qdot  = (float*)carve(NN*4);
  float* mmaxA = (float*)carve(NN*4);
  float* ssumA = (float*)carve(NN*4);
  float* aA    = (float*)carve(NN*4);
  float* bA    = (float*)carve(NN*4);
  float* cA    = (float*)carve(NN*4);
  float* fitA  = (float*)carve(NN*4);
  float* fitk  = (float*)carve(KC*4);
  float* wA2   = (float*)carve((HH+1)*4);
  float* wD    = (float*)carve((size_t)E2*4);
  int* rowD = (int*)carve((NN+1)*4);
  int* rowS = (int*)carve((NN+1)*4);
  int* cntD = (int*)carve(NN*4);
  int* cntS = (int*)carve(NN*4);
  int* curD = (int*)carve(NN*4);
  int* curS = (int*)carve(NN*4);
  int* colD = (int*)carve((size_t)E2*4);
  int* dstS = (int*)carve((size_t)E2*4);
  int* mapSD= (int*)carve((size_t)E2*4);
  int2* kwS = (int2*)carve((size_t)E2*8);
  unsigned* offsD = (unsigned*)carve((size_t)E2*4);
  __half* wHD = (__half*)carve((size_t)E2*2);
  int* perm = (int*)carve(KC*4);
  int* kcol = (int*)carve(NN*4);
  int* deg3 = (int*)carve(KC*4);

  k_zero_init<<<NN/256, 256, 0, stream>>>(cntD, cntS, deg3, out);
  k_count<<<(E2+255)/256, 256, 0, stream>>>(ei, cntD, cntS);
  k_scan<<<1, 1024, 0, stream>>>(cntD, cntS, rowD, rowS, curD, curS);
  k_scatter<<<(E2+255)/256, 256, 0, stream>>>(ei, curD, curS, colD, dstS, mapSD);

  // conv0 / conv1 (edge-mean + linear + colmean fused)
  k_eml<<<NN/16, 512, 0, stream>>>(x, rowD, colD, c0Wrel, c0brel, c0Wroot, x1, NN, out + 0);
  k_eml<<<NN/16, 512, 0, stream>>>(x1, rowD, colD, c1Wrel, c1brel, c1Wroot, x2b, NN, out + 128);

  // ASAP pool
  k_wprep<<<1, 128, 0, stream>>>(Wlin, blin, Watt, wA2);
  k_xdot<<<NN, 128, 0, stream>>>(x2b, Watt, xdot);
  k_pool<<<NN, 128, 0, stream>>>(x2b, rowD, colD, xdot, wA2, batt,
                                 W1, b1, W2, W3, b3,
                                 qdot, mmaxA, ssumA, xnew, wD, aA, bA, cA);
  k_fit<<<NN, 128, 0, stream>>>(rowD, colD, aA, bA, cA, fitA);
  k_sel<<<1, 1024, 0, stream>>>(fitA, perm, fitk, kcol);
  k_wS<<<(E2+255)/256, 256, 0, stream>>>(mapSD, dstS, kcol, wD, colD, kwS, offsD, wHD);
  k_U<<<NN, 256, 0, stream>>>(rowS, dstS, kwS, U);
  k_A2B<<<A2B_RT*8, 256, 0, stream>>>(rowD, offsD, wHD, perm, U, A2T, deg3);
  k_ztail<<<(A2P*(A2P-KC)+255)/256, 256, 0, stream>>>(A2T);

  // conv2 (MFMA K-split 4; partial-sum + deg-mean + colmean fused into k_lin2)
  k_xpt<<<A2P/64, 256, 0, stream>>>(xnew, perm, fitk, xp, Xt);
  k_mm<<<(A2P/32)*4, 256, 0, stream>>>(A2T, Xt, part);
  k_lin2<<<(KC+15)/16, 256, 0, stream>>>(part, deg3, xp,
                                         c2Wrel, c2brel, c2Wroot, x3, KC, out + 256);

  // conv3 (x4 never materialized; only its column-mean is needed)
  k_xt<<<A2P/64, 256, 0, stream>>>(x3, Xt);
  k_mm<<<(A2P/32)*4, 256, 0, stream>>>(A2T, Xt, part);
  k_lin2<<<(KC+15)/16, 256, 0, stream>>>(part, deg3, x3,
                                         c3Wrel, c3brel, c3Wroot, nullptr, KC, out + 384);
}

// Round 12
// 398.499 us; speedup vs baseline: 1.0626x; 1.0626x over previous
//
#include <hip/hip_runtime.h>
#include <hip/hip_fp16.h>
#include <math.h>

namespace {

constexpr int NN = 4096;
constexpr int EE = 131072;
constexpr int E2 = EE + NN;      // 135168 pool edges (orig + self loops)
constexpr int HH = 128;
constexpr int KC = 3277;         // ceil(0.8*4096)
constexpr int UP = 3584;         // U row stride (8*448)
constexpr int A2P = 3328;        // A2 row/col padded dim

typedef _Float16 f16x8 __attribute__((ext_vector_type(8)));
typedef _Float16 f16x4 __attribute__((ext_vector_type(4)));
typedef float f32x4 __attribute__((ext_vector_type(4)));

constexpr int A2B_RT = (KC + 3) / 4;   // 820 row-groups (4 waves x 1 row)
constexpr int KQ = A2P / 4;             // 832 K-quarter for k_mm

__device__ __forceinline__ float lrelu02(float x){ return x > 0.f ? x : 0.2f * x; }

__device__ __forceinline__ float redSum128(float* red, int t, float v){
  red[t] = v; __syncthreads();
  #pragma unroll
  for (int s = 64; s > 0; s >>= 1){ if (t < s) red[t] += red[t + s]; __syncthreads(); }
  float r = red[0]; __syncthreads();
  return r;
}
__device__ __forceinline__ float redMax128(float* red, int t, float v){
  red[t] = v; __syncthreads();
  #pragma unroll
  for (int s = 64; s > 0; s >>= 1){ if (t < s) red[t] = fmaxf(red[t], red[t + s]); __syncthreads(); }
  float r = red[0]; __syncthreads();
  return r;
}

__global__ void k_zero_init(int* cntD, int* cntS, int* deg, float* out){
  int i = blockIdx.x * blockDim.x + threadIdx.x;
  if (i < NN){ cntD[i] = 0; cntS[i] = 0; }
  if (i < KC) deg[i] = 0;
  if (i < 512) out[i] = 0.f;
}

__global__ void k_count(const int* __restrict__ ei, int* cntD, int* cntS){
  int e = blockIdx.x * blockDim.x + threadIdx.x;
  if (e >= E2) return;
  int u, v;
  if (e < EE){ u = ei[e]; v = ei[EE + e]; } else { u = e - EE; v = u; }
  atomicAdd(&cntD[v], 1);
  atomicAdd(&cntS[u], 1);
}

__global__ void k_scan(const int* cntD, const int* cntS, int* rowD, int* rowS, int* curD, int* curS){
  __shared__ int sc[1024];
  int t = threadIdx.x;
  for (int pass = 0; pass < 2; ++pass){
    const int* cnt = pass ? cntS : cntD;
    int* row = pass ? rowS : rowD;
    int* cur = pass ? curS : curD;
    int c0 = cnt[t*4+0], c1 = cnt[t*4+1], c2 = cnt[t*4+2], c3 = cnt[t*4+3];
    int tot = c0 + c1 + c2 + c3;
    sc[t] = tot; __syncthreads();
    for (int offs = 1; offs < 1024; offs <<= 1){
      int v = (t >= offs) ? sc[t - offs] : 0;
      __syncthreads();
      sc[t] += v;
      __syncthreads();
    }
    int excl = sc[t] - tot;
    int r0 = excl, r1 = r0 + c0, r2 = r1 + c1, r3 = r2 + c2;
    row[t*4+0] = r0; row[t*4+1] = r1; row[t*4+2] = r2; row[t*4+3] = r3;
    cur[t*4+0] = r0; cur[t*4+1] = r1; cur[t*4+2] = r2; cur[t*4+3] = r3;
    if (t == 1023) row[NN] = r3 + c3;
    __syncthreads();
  }
}

__global__ void k_scatter(const int* __restrict__ ei, int* curD, int* curS,
                          int* colD, int* dstS, int* mapSD){
  int e = blockIdx.x * blockDim.x + threadIdx.x;
  if (e >= E2) return;
  int u, v;
  if (e < EE){ u = ei[e]; v = ei[EE + e]; } else { u = e - EE; v = u; }
  int p = atomicAdd(&curD[v], 1); colD[p] = u;
  int q = atomicAdd(&curS[u], 1); dstS[q] = v; mapSD[q] = p;
}

// mean over in-neighbors (original edges only -> skip the self loop entry u==v)
__global__ void k_edge_mean(const float* __restrict__ xin, const int* __restrict__ rowD,
                            const int* __restrict__ colD, float* __restrict__ meanb){
  int v = blockIdx.x, t = threadIdx.x;
  int beg = rowD[v], end = rowD[v+1];
  float acc = 0.f;
  int p = beg;
  for (; p + 8 <= end; p += 8){
    int u0 = colD[p],   u1 = colD[p+1], u2 = colD[p+2], u3 = colD[p+3];
    int u4 = colD[p+4], u5 = colD[p+5], u6 = colD[p+6], u7 = colD[p+7];
    float a0 = xin[(size_t)u0*HH + t];
    float a1 = xin[(size_t)u1*HH + t];
    float a2 = xin[(size_t)u2*HH + t];
    float a3 = xin[(size_t)u3*HH + t];
    float a4 = xin[(size_t)u4*HH + t];
    float a5 = xin[(size_t)u5*HH + t];
    float a6 = xin[(size_t)u6*HH + t];
    float a7 = xin[(size_t)u7*HH + t];
    if (u0 != v) acc += a0;
    if (u1 != v) acc += a1;
    if (u2 != v) acc += a2;
    if (u3 != v) acc += a3;
    if (u4 != v) acc += a4;
    if (u5 != v) acc += a5;
    if (u6 != v) acc += a6;
    if (u7 != v) acc += a7;
  }
  for (; p < end; ++p){ int u = colD[p]; if (u != v) acc += xin[(size_t)u*HH + t]; }
  float dg = (float)(end - beg - 1);
  meanb[v*HH + t] = acc / fmaxf(dg, 1.f);
}

// xout = relu(meanb @ Wrel^T + brel + xin @ Wroot^T); fused column-mean atomic into cmout.
__global__ void k_lin(const float* __restrict__ meanb, const float* __restrict__ xin,
                      const float* __restrict__ Wrel, const float* __restrict__ brel,
                      const float* __restrict__ Wroot, float* __restrict__ xout, int rows,
                      float* __restrict__ cmout){
  __shared__ float ms[16][HH];
  __shared__ float xs[16][HH];
  __shared__ float cmred[256];
  int tid = threadIdx.x;
  int r0 = blockIdx.x * 16;
  for (int l = tid; l < 16*HH; l += 256){
    int r = l >> 7, c = l & 127; int gr = r0 + r;
    float mv = 0.f, xv = 0.f;
    if (gr < rows){ mv = meanb[(size_t)gr*HH + c]; xv = xin[(size_t)gr*HH + c]; }
    ms[r][c] = mv; xs[r][c] = xv;
  }
  __syncthreads();
  int h = tid & 127, hgrp = tid >> 7;
  float acc[8] = {0.f,0.f,0.f,0.f,0.f,0.f,0.f,0.f};
  for (int c = 0; c < HH; ++c){
    float wr = Wrel[h*HH + c], wo = Wroot[h*HH + c];
    #pragma unroll
    for (int r = 0; r < 8; ++r) acc[r] += ms[hgrp*8 + r][c]*wr + xs[hgrp*8 + r][c]*wo;
  }
  float bb = brel[h];
  float csum = 0.f;
  #pragma unroll
  for (int r = 0; r < 8; ++r){
    int gr = r0 + hgrp*8 + r;
    if (gr < rows){
      float val = fmaxf(acc[r] + bb, 0.f);
      xout[(size_t)gr*HH + h] = val;
      csum += val;
    }
  }
  cmred[tid] = csum; __syncthreads();
  if (tid < 128) atomicAdd(&cmout[h], (cmred[tid] + cmred[tid + 128]) / (float)rows);
}

// dense-conv linear: mean from 4 K-quarter partials / deg; optional xout; fused column-mean.
__global__ void k_lin2(const float* __restrict__ part, const int* __restrict__ deg,
                       const float* __restrict__ xin,
                       const float* __restrict__ Wrel, const float* __restrict__ brel,
                       const float* __restrict__ Wroot, float* __restrict__ xout, int rows,
                       float* __restrict__ cmout){
  __shared__ float ms[16][HH];
  __shared__ float xs[16][HH];
  __shared__ float cmred[256];
  const float* p0 = part;
  const float* p1 = part + (size_t)KC*HH;
  const float* p2 = part + (size_t)2*KC*HH;
  const float* p3 = part + (size_t)3*KC*HH;
  int tid = threadIdx.x;
  int r0 = blockIdx.x * 16;
  for (int l = tid; l < 16*HH; l += 256){
    int r = l >> 7, c = l & 127; int gr = r0 + r;
    float mv = 0.f, xv = 0.f;
    if (gr < rows){
      size_t idx = (size_t)gr*HH + c;
      float d = fmaxf((float)deg[gr], 1.f);
      mv = ((p0[idx] + p1[idx]) + (p2[idx] + p3[idx])) / d;
      xv = xin[idx];
    }
    ms[r][c] = mv; xs[r][c] = xv;
  }
  __syncthreads();
  int h = tid & 127, hgrp = tid >> 7;
  float acc[8] = {0.f,0.f,0.f,0.f,0.f,0.f,0.f,0.f};
  for (int c = 0; c < HH; ++c){
    float wr = Wrel[h*HH + c], wo = Wroot[h*HH + c];
    #pragma unroll
    for (int r = 0; r < 8; ++r) acc[r] += ms[hgrp*8 + r][c]*wr + xs[hgrp*8 + r][c]*wo;
  }
  float bb = brel[h];
  float csum = 0.f;
  #pragma unroll
  for (int r = 0; r < 8; ++r){
    int gr = r0 + hgrp*8 + r;
    if (gr < rows){
      float val = fmaxf(acc[r] + bb, 0.f);
      if (xout) xout[(size_t)gr*HH + h] = val;
      csum += val;
    }
  }
  cmred[tid] = csum; __syncthreads();
  if (tid < 128) atomicAdd(&cmout[h], (cmred[tid] + cmred[tid + 128]) / (float)rows);
}

// wA2[c] = sum_h wattA[h]*Wlin[h,c];  wA2[HH] = sum_h blin[h]*wattA[h]
__global__ void k_wprep(const float* __restrict__ Wlin, const float* __restrict__ blin,
                        const float* __restrict__ Watt, float* __restrict__ wA2){
  int c = threadIdx.x;
  float s = 0.f;
  for (int hh = 0; hh < HH; ++hh) s += Watt[hh] * Wlin[hh*HH + c];
  wA2[c] = s;
  if (c == 0){
    float q = 0.f;
    for (int hh = 0; hh < HH; ++hh) q += blin[hh] * Watt[hh];
    wA2[HH] = q;
  }
}

__global__ void k_xdot(const float* __restrict__ x2, const float* __restrict__ Watt, float* __restrict__ xdot){
  __shared__ float red[128];
  int n = blockIdx.x, t = threadIdx.x;
  float v = redSum128(red, t, x2[(size_t)n*HH + t] * Watt[HH + t]);
  if (t == 0) xdot[n] = v;
}

// per dst node v: xq max -> qdot; edge-softmax stats; x_new; wD; fused LEConv partials.
__global__ void k_pool(const float* __restrict__ x2, const int* __restrict__ rowD, const int* __restrict__ colD,
                       const float* __restrict__ xdotA, const float* __restrict__ wA2, const float* __restrict__ battp,
                       const float* __restrict__ W1, const float* __restrict__ b1,
                       const float* __restrict__ W2, const float* __restrict__ W3, const float* __restrict__ b3,
                       float* qdotA, float* mA, float* sA, float* __restrict__ xnew, float* __restrict__ wD,
                       float* aA, float* bA, float* cA){
  __shared__ float red[128];
  __shared__ float wmem[128];
  __shared__ int uc[128];
  int v = blockIdx.x, t = threadIdx.x;
  int beg = rowD[v], end = rowD[v+1];
  float batt = battp[0];
  float mx = -3.402823466e38f;
  int p = beg;
  for (; p + 4 <= end; p += 4){
    float a0 = x2[(size_t)colD[p]*HH + t];
    float a1 = x2[(size_t)colD[p+1]*HH + t];
    float a2 = x2[(size_t)colD[p+2]*HH + t];
    float a3 = x2[(size_t)colD[p+3]*HH + t];
    mx = fmaxf(fmaxf(fmaxf(fmaxf(mx, a0), a1), a2), a3);
  }
  for (; p < end; ++p) mx = fmaxf(mx, x2[(size_t)colD[p]*HH + t]);
  float qd = redSum128(red, t, mx * wA2[t]) + wA2[HH];
  float lm = -3.402823466e38f;
  for (p = beg + t; p < end; p += 128) lm = fmaxf(lm, lrelu02(qd + xdotA[colD[p]] + batt));
  float mm = redMax128(red, t, lm);
  float ls = 0.f;
  for (p = beg + t; p < end; p += 128) ls += expf(lrelu02(qd + xdotA[colD[p]] + batt) - mm);
  float ss = redSum128(red, t, ls);
  float acc = 0.f;
  for (int basep = beg; basep < end; basep += 128){
    int cnt = min(128, end - basep);
    if (t < cnt){
      int u = colD[basep + t];
      uc[t] = u;
      float w = expf(lrelu02(qd + xdotA[u] + batt) - mm) / ss;
      wmem[t] = w;
      wD[basep + t] = w;
    }
    __syncthreads();
    int i = 0;
    for (; i + 4 <= cnt; i += 4){
      float a0 = x2[(size_t)uc[i]*HH + t];
      float a1 = x2[(size_t)uc[i+1]*HH + t];
      float a2 = x2[(size_t)uc[i+2]*HH + t];
      float a3 = x2[(size_t)uc[i+3]*HH + t];
      acc += wmem[i]*a0 + wmem[i+1]*a1 + wmem[i+2]*a2 + wmem[i+3]*a3;
    }
    for (; i < cnt; ++i) acc += wmem[i] * x2[(size_t)uc[i]*HH + t];
    __syncthreads();
  }
  xnew[(size_t)v*HH + t] = acc;
  float s1 = redSum128(red, t, acc * W1[t]);
  float s2 = redSum128(red, t, acc * W2[t]);
  float s3 = redSum128(red, t, acc * W3[t]);
  if (t == 0){
    qdotA[v] = qd; mA[v] = mm; sA[v] = ss;
    aA[v] = s1 + b1[0]; bA[v] = s2; cA[v] = s3 + b3[0];
  }
}

__global__ void k_fit(const int* __restrict__ rowD, const int* __restrict__ colD,
                      const float* __restrict__ aA, const float* __restrict__ bA, const float* __restrict__ cA,
                      float* __restrict__ fitA){
  __shared__ float red[128];
  int v = blockIdx.x, t = threadIdx.x;
  int beg = rowD[v], end = rowD[v+1];
  float la = 0.f;
  for (int p = beg + t; p < end; p += 128) la += aA[colD[p]];
  float s = redSum128(red, t, la);
  if (t == 0){
    float g = s - (float)(end - beg) * bA[v] + cA[v];
    fitA[v] = 1.f / (1.f + expf(-g));
  }
}

// Exact top-K SET selection via radix-select (1 block, 1024 threads).
__global__ void k_sel(const float* __restrict__ fitA, int* perm, float* fitk, int* kcol){
  __shared__ unsigned keys[NN];
  __shared__ int hist[256];
  __shared__ int sc[1024];
  __shared__ int bc[2];
  int t = threadIdx.x;
  #pragma unroll
  for (int r = 0; r < 4; ++r){
    int i = t + r*1024;
    unsigned b = __float_as_uint(fitA[i]);
    keys[i] = (b & 0x80000000u) ? ~b : (b ^ 0x80000000u);
  }
  __syncthreads();
  unsigned prefix = 0;
  int kneed = KC;
  #pragma unroll
  for (int round = 0; round < 4; ++round){
    int shift = 24 - round*8;
    unsigned pmask = (round == 0) ? 0u : (0xFFFFFFFFu << (shift + 8));
    if (t < 256) hist[t] = 0;
    __syncthreads();
    #pragma unroll
    for (int r = 0; r < 4; ++r){
      unsigned kv = keys[t + r*1024];
      if ((kv & pmask) == prefix)
        atomicAdd(&hist[(kv >> shift) & 0xFF], 1);
    }
    __syncthreads();
    if (t == 0){
      int acc = 0, chosen = 0, rem = kneed;
      for (int bkt = 255; bkt >= 0; --bkt){
        int c = hist[bkt];
        if (acc + c >= kneed){ chosen = bkt; rem = kneed - acc; break; }
        acc += c;
      }
      bc[0] = chosen; bc[1] = rem;
    }
    __syncthreads();
    prefix |= ((unsigned)bc[0]) << shift;
    kneed = bc[1];
    __syncthreads();
  }
  unsigned T = prefix;
  int need_eq = kneed;
  int cnt[4]; int tot = 0;
  #pragma unroll
  for (int r = 0; r < 4; ++r){
    unsigned kv = keys[t*4 + r];
    int g = (kv > T) ? 1 : 0;
    int e = (kv == T) ? 1 : 0;
    cnt[r] = (g << 16) | e;
    tot += cnt[r];
  }
  sc[t] = tot; __syncthreads();
  for (int offs = 1; offs < 1024; offs <<= 1){
    int v = (t >= offs) ? sc[t - offs] : 0;
    __syncthreads();
    sc[t] += v;
    __syncthreads();
  }
  int gtot = sc[1023] >> 16;
  int run = sc[t] - tot;
  #pragma unroll
  for (int r = 0; r < 4; ++r){
    int i = t*4 + r;
    int g = cnt[r] >> 16, e = cnt[r] & 0xFFFF;
    int gpos = run >> 16, epos = run & 0xFFFF;
    int pos = -1;
    if (g) pos = gpos;
    else if (e && epos < need_eq) pos = gtot + epos;
    if (pos >= 0){ perm[pos] = i; fitk[pos] = fitA[i]; kcol[i] = pos; }
    else kcol[i] = -1;
    run += cnt[r];
  }
}

// fused: xp[j,:] = xnew[perm[j],:]*fitk[j]  AND  Xt[h][j] = f16(xp[j][h])
__global__ void k_xpt(const float* __restrict__ xnew, const int* __restrict__ perm,
                      const float* __restrict__ fitk, float* __restrict__ xp,
                      __half* __restrict__ Xt){
  __shared__ float T2[64][129];
  int t = threadIdx.x;
  int j0 = blockIdx.x * 64;
  for (int l = t; l < 64*32; l += 256){
    int jl = l >> 5, hg = (l & 31) * 4;
    int j = j0 + jl;
    float4 v = make_float4(0.f, 0.f, 0.f, 0.f);
    if (j < KC){
      float f = fitk[j];
      const float* src = xnew + (size_t)perm[j]*HH + hg;
      v.x = src[0]*f; v.y = src[1]*f; v.z = src[2]*f; v.w = src[3]*f;
      *(float4*)(xp + (size_t)j*HH + hg) = v;
    }
    T2[jl][hg] = v.x; T2[jl][hg+1] = v.y; T2[jl][hg+2] = v.z; T2[jl][hg+3] = v.w;
  }
  __syncthreads();
  for (int idx = t; idx < 128*64; idx += 256){
    int h = idx >> 6, jl = idx & 63;
    Xt[(size_t)h*A2P + j0 + jl] = __float2half(T2[jl][h]);
  }
}

// src-ordered packed (kcol, w) for k_U; dst-ordered byte-offset + f16 weight for k_A2B
__global__ void k_wS(const int* __restrict__ mapSD, const int* __restrict__ dstS,
                     const int* __restrict__ kcol, const float* __restrict__ wD,
                     const int* __restrict__ colD,
                     int2* __restrict__ kwS, unsigned* __restrict__ offsD,
                     __half* __restrict__ wHD){
  int q = blockIdx.x * blockDim.x + threadIdx.x;
  if (q >= E2) return;
  float w = wD[mapSD[q]];
  int k = kcol[dstS[q]];
  kwS[q] = make_int2(k, __float_as_int(w));
  offsD[q] = (unsigned)colD[q] * (UP*2);
  wHD[q] = __float2half(wD[q]);
}

// U[n,:] = (A @ S)[n,:]. Flattened 2-hop edge list per block: full 256-thread utilization
// (old version had only ~deg(33)/256 threads active in the inner scatter loop).
__global__ void k_U(const int* __restrict__ rowS, const int* __restrict__ dstS,
                    const int2* __restrict__ kwS, __half* __restrict__ U){
  __shared__ float acc[UP];   // 14 KB
  __shared__ int pref[129];
  __shared__ int nbase[128];
  int t = threadIdx.x, n = blockIdx.x;
  for (int i = t; i < UP; i += 256) acc[i] = 0.f;
  int b = rowS[n], e = rowS[n+1];
  __syncthreads();
  for (int cb = b; cb < e; cb += 128){
    int cnt = min(128, e - cb);
    if (t < cnt){
      int j = dstS[cb + t];
      int b2 = rowS[j];
      nbase[t] = b2;
      pref[t+1] = rowS[j+1] - b2;
    }
    if (t == 0) pref[0] = 0;
    __syncthreads();
    if (t == 0){
      for (int i = 0; i < cnt; ++i) pref[i+1] += pref[i];
    }
    __syncthreads();
    int total = pref[cnt];
    for (int idx = t; idx < total; idx += 256){
      int lo = 0, hi = cnt - 1;
      while (lo < hi){
        int mid = (lo + hi + 1) >> 1;
        if (pref[mid] <= idx) lo = mid; else hi = mid - 1;
      }
      int q = nbase[lo] + (idx - pref[lo]);
      int2 kw = kwS[q];
      if (kw.x >= 0) atomicAdd(&acc[kw.x], __int_as_float(kw.y));
    }
    __syncthreads();
  }
  __half2* Ur = (__half2*)(U + (size_t)n * UP);
  for (int i = t; i < UP/2; i += 256)
    Ur[i] = __halves2half2(__float2half(acc[2*i]), __float2half(acc[2*i+1]));
}

// A2[k1, cc*448 .. +447] (R9 single-row, 8-deep ILP, row-major coalesced writes).
// 8 col-chunks of 448 (XCD-pinned); fused nonzero count -> deg.
__global__ void k_A2B(const int* __restrict__ rowD,
                      const unsigned* __restrict__ offsD, const __half* __restrict__ wHDh,
                      const int* __restrict__ perm,
                      const __half* __restrict__ Uh, __half* __restrict__ A2,
                      int* __restrict__ deg){
  int cc = blockIdx.x & 7;
  int rt = blockIdx.x >> 3;
  int t = threadIdx.x;
  int w = t >> 6, lane = t & 63;
  int k1 = rt*4 + w;
  if (k1 >= KC) return;
  bool act = lane < 56;
  unsigned laneoff = (unsigned)(cc*448*2 + lane*16);
  const char* Ub = (const char*)Uh;
  const _Float16* wHD = (const _Float16*)wHDh;

  f16x8 accA = (f16x8)(_Float16)0, accB = (f16x8)(_Float16)0;
  f16x8 accC = (f16x8)(_Float16)0, accD = (f16x8)(_Float16)0;
  int v1 = perm[k1];
  int p = rowD[v1], end = rowD[v1+1];

  int pre = (8 - (p & 7)) & 7;
  if (pre > end - p) pre = end - p;
  for (int z = 0; z < pre; ++z, ++p){
    unsigned off = offsD[p];
    _Float16 w0 = wHD[p];
    if (act){
      f16x8 u = *(const f16x8*)(Ub + (size_t)(off + laneoff));
      accA += u * w0;
    }
  }
  for (; p + 8 <= end; p += 8){
    uint4 oA = *(const uint4*)(offsD + p);
    uint4 oB = *(const uint4*)(offsD + p + 4);
    f16x8 wv = *(const f16x8*)(wHD + p);
    if (act){
      f16x8 u0 = *(const f16x8*)(Ub + (size_t)(oA.x + laneoff));
      f16x8 u1 = *(const f16x8*)(Ub + (size_t)(oA.y + laneoff));
      f16x8 u2 = *(const f16x8*)(Ub + (size_t)(oA.z + laneoff));
      f16x8 u3 = *(const f16x8*)(Ub + (size_t)(oA.w + laneoff));
      f16x8 u4 = *(const f16x8*)(Ub + (size_t)(oB.x + laneoff));
      f16x8 u5 = *(const f16x8*)(Ub + (size_t)(oB.y + laneoff));
      f16x8 u6 = *(const f16x8*)(Ub + (size_t)(oB.z + laneoff));
      f16x8 u7 = *(const f16x8*)(Ub + (size_t)(oB.w + laneoff));
      accA += u0 * wv[0];
      accB += u1 * wv[1];
      accC += u2 * wv[2];
      accD += u3 * wv[3];
      accA += u4 * wv[4];
      accB += u5 * wv[5];
      accC += u6 * wv[6];
      accD += u7 * wv[7];
    }
  }
  for (; p < end; ++p){
    unsigned off = offsD[p];
    _Float16 w0 = wHD[p];
    if (act){
      f16x8 u = *(const f16x8*)(Ub + (size_t)(off + laneoff));
      accB += u * w0;
    }
  }
  f16x8 acc = (accA + accB) + (accC + accD);

  int col0 = cc*448 + lane * 8;
  f16x8 o = (f16x8)(_Float16)0;
  int c = 0;
  if (act){
    #pragma unroll
    for (int e = 0; e < 8; ++e){
      int col = col0 + e;
      _Float16 hv = (col == k1 || col >= KC) ? (_Float16)0 : acc[e];
      o[e] = hv;
      c += (hv != (_Float16)0) ? 1 : 0;
    }
  }
  #pragma unroll
  for (int s = 32; s > 0; s >>= 1) c += __shfl_down(c, s);
  if (lane == 0) atomicAdd(&deg[k1], c);
  if (act && col0 + 8 <= A2P)
    *(f16x8*)(A2 + (size_t)k1 * A2P + col0) = o;
}

// LDS-tiled transpose: A2T[i][j] = A2[j][i]; rows j >= KC read as zero.
__global__ void k_tr(const __half* __restrict__ A2, __half* __restrict__ A2T){
  __shared__ float tile[64][65];
  int t = threadIdx.x;
  int i0 = blockIdx.x * 64, j0 = blockIdx.y * 64;
  int sl = t & 7;
  #pragma unroll
  for (int p = 0; p < 2; ++p){
    int jl = (t >> 3) + p*32;
    int j = j0 + jl;
    f16x8 v;
    if (j < KC) v = *(const f16x8*)(A2 + (size_t)j*A2P + i0 + sl*8);
    else v = (f16x8)(_Float16)0;
    #pragma unroll
    for (int e = 0; e < 8; ++e) tile[jl][sl*8 + e] = (float)v[e];
  }
  __syncthreads();
  #pragma unroll
  for (int p = 0; p < 2; ++p){
    int il = (t >> 3) + p*32;
    int i = i0 + il;
    f16x8 o;
    #pragma unroll
    for (int e = 0; e < 8; ++e) o[e] = (_Float16)tile[sl*8 + e][il];
    *(f16x8*)(A2T + (size_t)i*A2P + j0 + sl*8) = o;
  }
}

// Xt[h][j] = (f16) X[j][h], zero-padded for j >= KC.
__global__ void k_xt(const float* __restrict__ X, __half* __restrict__ Xt){
  __shared__ float T2[64][129];
  int t = threadIdx.x;
  int j0 = blockIdx.x * 64;
  for (int l = t; l < 64*32; l += 256){
    int jl = l >> 5, hg = (l & 31) * 4;
    int j = j0 + jl;
    float4 v = make_float4(0.f, 0.f, 0.f, 0.f);
    if (j < KC) v = *(const float4*)(X + (size_t)j*HH + hg);
    T2[jl][hg] = v.x; T2[jl][hg+1] = v.y; T2[jl][hg+2] = v.z; T2[jl][hg+3] = v.w;
  }
  __syncthreads();
  for (int idx = t; idx < 128*64; idx += 256){
    int h = idx >> 6, jl = idx & 63;
    Xt[(size_t)h*A2P + j0 + jl] = __float2half(T2[jl][h]);
  }
}

// MFMA dagg: 32i x 128h per block, K-split 4, atomic-free.
__global__ void k_mm(const __half* __restrict__ A2Th, const __half* __restrict__ Xth,
                     float* __restrict__ part){
  const _Float16* A2T = (const _Float16*)A2Th;
  const _Float16* Xt  = (const _Float16*)Xth;
  int t = threadIdx.x;
  int lane = t & 63, w = t >> 6;
  int i0 = (blockIdx.x >> 2) * 32;
  int kq = blockIdx.x & 3;
  int kbeg = kq * KQ;
  float* po = part + (size_t)kq * KC * HH;
  int l15 = lane & 15, lk = (lane >> 4) * 8;
  const _Float16* Ar0 = A2T + (size_t)(i0 + l15) * A2P + lk + kbeg;
  const _Float16* Ar1 = Ar0 + (size_t)16 * A2P;
  const _Float16* B0 = Xt + (size_t)(w*32 + l15) * A2P + lk + kbeg;
  const _Float16* B1 = B0 + (size_t)16 * A2P;
  f32x4 acc00 = (f32x4)0.f, acc01 = (f32x4)0.f;
  f32x4 acc10 = (f32x4)0.f, acc11 = (f32x4)0.f;
  for (int kk = 0; kk < KQ; kk += 64){
    f16x8 a00 = *(const f16x8*)(Ar0 + kk);
    f16x8 a01 = *(const f16x8*)(Ar0 + kk + 32);
    f16x8 a10 = *(const f16x8*)(Ar1 + kk);
    f16x8 a11 = *(const f16x8*)(Ar1 + kk + 32);
    f16x8 b00 = *(const f16x8*)(B0 + kk);
    f16x8 b01 = *(const f16x8*)(B1 + kk);
    f16x8 b10 = *(const f16x8*)(B0 + kk + 32);
    f16x8 b11 = *(const f16x8*)(B1 + kk + 32);
    acc00 = __builtin_amdgcn_mfma_f32_16x16x32_f16(a00, b00, acc00, 0, 0, 0);
    acc01 = __builtin_amdgcn_mfma_f32_16x16x32_f16(a00, b01, acc01, 0, 0, 0);
    acc10 = __builtin_amdgcn_mfma_f32_16x16x32_f16(a10, b00, acc10, 0, 0, 0);
    acc11 = __builtin_amdgcn_mfma_f32_16x16x32_f16(a10, b01, acc11, 0, 0, 0);
    acc00 = __builtin_amdgcn_mfma_f32_16x16x32_f16(a01, b10, acc00, 0, 0, 0);
    acc01 = __builtin_amdgcn_mfma_f32_16x16x32_f16(a01, b11, acc01, 0, 0, 0);
    acc10 = __builtin_amdgcn_mfma_f32_16x16x32_f16(a11, b10, acc10, 0, 0, 0);
    acc11 = __builtin_amdgcn_mfma_f32_16x16x32_f16(a11, b11, acc11, 0, 0, 0);
  }
  int rbase = (lane >> 4) * 4;
  #pragma unroll
  for (int r = 0; r < 4; ++r){
    int ia = i0 + rbase + r;
    int ib = ia + 16;
    if (ia < KC){
      po[(size_t)ia*HH + w*32 + l15] = acc00[r];
      po[(size_t)ia*HH + w*32 + 16 + l15] = acc01[r];
    }
    if (ib < KC){
      po[(size_t)ib*HH + w*32 + l15] = acc10[r];
      po[(size_t)ib*HH + w*32 + 16 + l15] = acc11[r];
    }
  }
}

} // namespace

extern "C" void kernel_launch(void* const* d_in, const int* in_sizes, int n_in,
                              void* d_out, int out_size, void* d_ws, size_t ws_size,
                              hipStream_t stream){
  (void)in_sizes; (void)n_in; (void)out_size; (void)ws_size;
  const float* x      = (const float*)d_in[0];
  const int*   ei     = (const int*)d_in[1];
  const float* c0Wrel = (const float*)d_in[2];
  const float* c0brel = (const float*)d_in[3];
  const float* c0Wroot= (const float*)d_in[4];
  const float* c1Wrel = (const float*)d_in[5];
  const float* c1brel = (const float*)d_in[6];
  const float* c1Wroot= (const float*)d_in[7];
  const float* c2Wrel = (const float*)d_in[8];
  const float* c2brel = (const float*)d_in[9];
  const float* c2Wroot= (const float*)d_in[10];
  const float* c3Wrel = (const float*)d_in[11];
  const float* c3brel = (const float*)d_in[12];
  const float* c3Wroot= (const float*)d_in[13];
  const float* Wlin   = (const float*)d_in[14];
  const float* blin   = (const float*)d_in[15];
  const float* Watt   = (const float*)d_in[16];
  const float* batt   = (const float*)d_in[17];
  const float* W1     = (const float*)d_in[18];
  const float* b1     = (const float*)d_in[19];
  const float* W2     = (const float*)d_in[20];
  const float* W3     = (const float*)d_in[21];
  const float* b3     = (const float*)d_in[22];
  float* out = (float*)d_out;

  char* base = (char*)d_ws;
  size_t off = 0;
  auto carve = [&](size_t bytes) -> void* {
    void* p = base + off;
    off += (bytes + 255) & ~(size_t)255;
    return p;
  };
  float* x1    = (float*)carve((size_t)NN*HH*4);
  float* x2b   = (float*)carve((size_t)NN*HH*4);
  float* meanb = (float*)carve((size_t)NN*HH*4);
  float* xnew  = (float*)carve((size_t)NN*HH*4);
  float* xp    = (float*)carve((size_t)KC*HH*4);
  float* x3    = (float*)carve((size_t)KC*HH*4);
  float* part  = (float*)carve((size_t)4*KC*HH*4);   // 4 K-quarter partials
  __half* A2   = (__half*)carve((size_t)KC*A2P*2);   // ~22 MB
  __half* U    = (__half*)carve((size_t)NN*UP*2);    // ~29 MB; dead after k_A2B -> reused as A2T
  __half* A2T  = U;
  __half* Xt   = (__half*)carve((size_t)HH*A2P*2);
  float* xdot  = (float*)carve(NN*4);
  float* qdot  = (float*)carve(NN*4);
  float* mmaxA = (float*)carve(NN*4);
  float* ssumA = (float*)carve(NN*4);
  float* aA    = (float*)carve(NN*4);
  float* bA    = (float*)carve(NN*4);
  float* cA    = (float*)carve(NN*4);
  float* fitA  = (float*)carve(NN*4);
  float* fitk  = (float*)carve(KC*4);
  float* wA2   = (float*)carve((HH+1)*4);
  float* wD    = (float*)carve((size_t)E2*4);
  int* rowD = (int*)carve((NN+1)*4);
  int* rowS = (int*)carve((NN+1)*4);
  int* cntD = (int*)carve(NN*4);
  int* cntS = (int*)carve(NN*4);
  int* curD = (int*)carve(NN*4);
  int* curS = (int*)carve(NN*4);
  int* colD = (int*)carve((size_t)E2*4);
  int* dstS = (int*)carve((size_t)E2*4);
  int* mapSD= (int*)carve((size_t)E2*4);
  int2* kwS = (int2*)carve((size_t)E2*8);
  unsigned* offsD = (unsigned*)carve((size_t)E2*4);
  __half* wHD = (__half*)carve((size_t)E2*2);
  int* perm = (int*)carve(KC*4);
  int* kcol = (int*)carve(NN*4);
  int* deg3 = (int*)carve(KC*4);

  k_zero_init<<<NN/256, 256, 0, stream>>>(cntD, cntS, deg3, out);
  k_count<<<(E2+255)/256, 256, 0, stream>>>(ei, cntD, cntS);
  k_scan<<<1, 1024, 0, stream>>>(cntD, cntS, rowD, rowS, curD, curS);
  k_scatter<<<(E2+255)/256, 256, 0, stream>>>(ei, curD, curS, colD, dstS, mapSD);

  // conv0 (colmean fused into k_lin)
  k_edge_mean<<<NN, 128, 0, stream>>>(x, rowD, colD, meanb);
  k_lin<<<(NN+15)/16, 256, 0, stream>>>(meanb, x, c0Wrel, c0brel, c0Wroot, x1, NN, out + 0);

  // conv1
  k_edge_mean<<<NN, 128, 0, stream>>>(x1, rowD, colD, meanb);
  k_lin<<<(NN+15)/16, 256, 0, stream>>>(meanb, x1, c1Wrel, c1brel, c1Wroot, x2b, NN, out + 128);

  // ASAP pool
  k_wprep<<<1, 128, 0, stream>>>(Wlin, blin, Watt, wA2);
  k_xdot<<<NN, 128, 0, stream>>>(x2b, Watt, xdot);
  k_pool<<<NN, 128, 0, stream>>>(x2b, rowD, colD, xdot, wA2, batt,
                                 W1, b1, W2, W3, b3,
                                 qdot, mmaxA, ssumA, xnew, wD, aA, bA, cA);
  k_fit<<<NN, 128, 0, stream>>>(rowD, colD, aA, bA, cA, fitA);
  k_sel<<<1, 1024, 0, stream>>>(fitA, perm, fitk, kcol);
  k_wS<<<(E2+255)/256, 256, 0, stream>>>(mapSD, dstS, kcol, wD, colD, kwS, offsD, wHD);
  k_U<<<NN, 256, 0, stream>>>(rowS, dstS, kwS, U);
  k_A2B<<<A2B_RT*8, 256, 0, stream>>>(rowD, offsD, wHD, perm, U, A2, deg3);

  // transpose A2 -> A2T (U is dead now; A2T aliases it)
  k_tr<<<dim3(A2P/64, A2P/64), 256, 0, stream>>>(A2, A2T);

  // conv2 (MFMA K-split 4; partial-sum + deg-mean + colmean fused into k_lin2)
  k_xpt<<<A2P/64, 256, 0, stream>>>(xnew, perm, fitk, xp, Xt);
  k_mm<<<(A2P/32)*4, 256, 0, stream>>>(A2T, Xt, part);
  k_lin2<<<(KC+15)/16, 256, 0, stream>>>(part, deg3, xp,
                                         c2Wrel, c2brel, c2Wroot, x3, KC, out + 256);

  // conv3 (x4 never materialized; only its column-mean is needed)
  k_xt<<<A2P/64, 256, 0, stream>>>(x3, Xt);
  k_mm<<<(A2P/32)*4, 256, 0, stream>>>(A2T, Xt, part);
  k_lin2<<<(KC+15)/16, 256, 0, stream>>>(part, deg3, x3,
                                         c3Wrel, c3brel, c3Wroot, nullptr, KC, out + 384);
}

// Round 13
// 368.644 us; speedup vs baseline: 1.1486x; 1.0810x over previous
//
#include <hip/hip_runtime.h>
#include <hip/hip_fp16.h>
#include <math.h>

namespace {

constexpr int NN = 4096;
constexpr int EE = 131072;
constexpr int E2 = EE + NN;      // 135168 pool edges (orig + self loops)
constexpr int HH = 128;
constexpr int KC = 3277;         // ceil(0.8*4096)
constexpr int UP = 3584;         // U row stride (8*448)
constexpr int A2P = 3328;        // A2 row/col padded dim

typedef _Float16 f16x8 __attribute__((ext_vector_type(8)));
typedef _Float16 f16x4 __attribute__((ext_vector_type(4)));
typedef float f32x4 __attribute__((ext_vector_type(4)));

constexpr int A2B_RT = (KC + 3) / 4;   // 820 row-groups (4 waves x 1 row)
constexpr int KQ = A2P / 4;             // 832 K-quarter for k_mm

__device__ __forceinline__ float lrelu02(float x){ return x > 0.f ? x : 0.2f * x; }

__device__ __forceinline__ float redSum128(float* red, int t, float v){
  red[t] = v; __syncthreads();
  #pragma unroll
  for (int s = 64; s > 0; s >>= 1){ if (t < s) red[t] += red[t + s]; __syncthreads(); }
  float r = red[0]; __syncthreads();
  return r;
}
__device__ __forceinline__ float redMax128(float* red, int t, float v){
  red[t] = v; __syncthreads();
  #pragma unroll
  for (int s = 64; s > 0; s >>= 1){ if (t < s) red[t] = fmaxf(red[t], red[t + s]); __syncthreads(); }
  float r = red[0]; __syncthreads();
  return r;
}

__global__ void k_zero_init(int* cntD, int* cntS, int* deg, float* out){
  int i = blockIdx.x * blockDim.x + threadIdx.x;
  if (i < NN){ cntD[i] = 0; cntS[i] = 0; }
  if (i < KC) deg[i] = 0;
  if (i < 512) out[i] = 0.f;
}

__global__ void k_count(const int* __restrict__ ei, int* cntD, int* cntS){
  int e = blockIdx.x * blockDim.x + threadIdx.x;
  if (e >= E2) return;
  int u, v;
  if (e < EE){ u = ei[e]; v = ei[EE + e]; } else { u = e - EE; v = u; }
  atomicAdd(&cntD[v], 1);
  atomicAdd(&cntS[u], 1);
}

__global__ void k_scan(const int* cntD, const int* cntS, int* rowD, int* rowS, int* curD, int* curS){
  __shared__ int sc[1024];
  int t = threadIdx.x;
  for (int pass = 0; pass < 2; ++pass){
    const int* cnt = pass ? cntS : cntD;
    int* row = pass ? rowS : rowD;
    int* cur = pass ? curS : curD;
    int c0 = cnt[t*4+0], c1 = cnt[t*4+1], c2 = cnt[t*4+2], c3 = cnt[t*4+3];
    int tot = c0 + c1 + c2 + c3;
    sc[t] = tot; __syncthreads();
    for (int offs = 1; offs < 1024; offs <<= 1){
      int v = (t >= offs) ? sc[t - offs] : 0;
      __syncthreads();
      sc[t] += v;
      __syncthreads();
    }
    int excl = sc[t] - tot;
    int r0 = excl, r1 = r0 + c0, r2 = r1 + c1, r3 = r2 + c2;
    row[t*4+0] = r0; row[t*4+1] = r1; row[t*4+2] = r2; row[t*4+3] = r3;
    cur[t*4+0] = r0; cur[t*4+1] = r1; cur[t*4+2] = r2; cur[t*4+3] = r3;
    if (t == 1023) row[NN] = r3 + c3;
    __syncthreads();
  }
}

__global__ void k_scatter(const int* __restrict__ ei, int* curD, int* curS,
                          int* colD, int* dstS, int* mapSD){
  int e = blockIdx.x * blockDim.x + threadIdx.x;
  if (e >= E2) return;
  int u, v;
  if (e < EE){ u = ei[e]; v = ei[EE + e]; } else { u = e - EE; v = u; }
  int p = atomicAdd(&curD[v], 1); colD[p] = u;
  int q = atomicAdd(&curS[u], 1); dstS[q] = v; mapSD[q] = p;
}

// prep: xh = f16(x); WH = f16 weights [W0rel|W0root|W1rel|W1root]; wprep (last block).
__global__ void k_prep(const float* __restrict__ x,
                       const float* __restrict__ W0rel, const float* __restrict__ W0root,
                       const float* __restrict__ W1rel, const float* __restrict__ W1root,
                       const float* __restrict__ Wlin, const float* __restrict__ blin,
                       const float* __restrict__ Watt,
                       __half* __restrict__ xh, __half* __restrict__ WH, float* __restrict__ wA2){
  int b = blockIdx.x;
  if (b < 2048){
    int i = b*256 + threadIdx.x;
    xh[i] = __float2half(x[i]);
  } else if (b < 2048 + 256){
    int i = (b - 2048)*256 + threadIdx.x;
    int m = i >> 14, o = i & 16383;
    const float* src = (m == 0) ? W0rel : (m == 1) ? W0root : (m == 2) ? W1rel : W1root;
    WH[i] = __float2half(src[o]);
  } else {
    int c = threadIdx.x;
    if (c < 128){
      float s = 0.f;
      for (int hh = 0; hh < HH; ++hh) s += Watt[hh] * Wlin[hh*HH + c];
      wA2[c] = s;
      if (c == 0){
        float q = 0.f;
        for (int hh = 0; hh < HH; ++hh) q += blin[hh] * Watt[hh];
        wA2[HH] = q;
      }
    }
  }
}

// mean over in-neighbors, f16 input rows, f16 output (f32 accumulate).
__global__ void k_edge_meanH(const __half* __restrict__ xinh, const int* __restrict__ rowD,
                             const int* __restrict__ colD, __half* __restrict__ meanbh){
  int v = blockIdx.x, t = threadIdx.x;
  int beg = rowD[v], end = rowD[v+1];
  float acc = 0.f;
  int p = beg;
  for (; p + 8 <= end; p += 8){
    int u0 = colD[p],   u1 = colD[p+1], u2 = colD[p+2], u3 = colD[p+3];
    int u4 = colD[p+4], u5 = colD[p+5], u6 = colD[p+6], u7 = colD[p+7];
    float a0 = __half2float(xinh[(size_t)u0*HH + t]);
    float a1 = __half2float(xinh[(size_t)u1*HH + t]);
    float a2 = __half2float(xinh[(size_t)u2*HH + t]);
    float a3 = __half2float(xinh[(size_t)u3*HH + t]);
    float a4 = __half2float(xinh[(size_t)u4*HH + t]);
    float a5 = __half2float(xinh[(size_t)u5*HH + t]);
    float a6 = __half2float(xinh[(size_t)u6*HH + t]);
    float a7 = __half2float(xinh[(size_t)u7*HH + t]);
    if (u0 != v) acc += a0;
    if (u1 != v) acc += a1;
    if (u2 != v) acc += a2;
    if (u3 != v) acc += a3;
    if (u4 != v) acc += a4;
    if (u5 != v) acc += a5;
    if (u6 != v) acc += a6;
    if (u7 != v) acc += a7;
  }
  for (; p < end; ++p){ int u = colD[p]; if (u != v) acc += __half2float(xinh[(size_t)u*HH + t]); }
  float dg = (float)(end - beg - 1);
  meanbh[(size_t)v*HH + t] = __float2half(acc / fmaxf(dg, 1.f));
}

// MFMA GraphConv linear: xout = relu([meanbh|xinh] @ [Wrel|Wroot]^T + brel).
// grid NN/16, 256 thr = 4 waves; wave w covers h in [w*32, w*32+32). Fused colmean.
// Writes f32 xout and f16 xouth.
__global__ void k_linM(const __half* __restrict__ mh, const __half* __restrict__ xinh,
                       const __half* __restrict__ WHh, int woff,
                       const float* __restrict__ brel,
                       float* __restrict__ xout, __half* __restrict__ xouth,
                       float* __restrict__ cmout){
  int t = threadIdx.x, lane = t & 63, w = t >> 6;
  int r0 = blockIdx.x * 16;
  int l15 = lane & 15, lk = (lane >> 4) * 8;
  const _Float16* WH = (const _Float16*)WHh;
  const _Float16* Am = (const _Float16*)mh + (size_t)(r0 + l15)*HH + lk;
  const _Float16* Ax = (const _Float16*)xinh + (size_t)(r0 + l15)*HH + lk;
  const _Float16* Brel0 = WH + woff + (size_t)(w*32 + l15)*HH + lk;
  const _Float16* Brel1 = Brel0 + (size_t)16*HH;
  const _Float16* Broot0 = Brel0 + 16384;
  const _Float16* Broot1 = Brel1 + 16384;
  f32x4 acc0 = (f32x4)0.f, acc1 = (f32x4)0.f;
  #pragma unroll
  for (int kk = 0; kk < HH; kk += 32){
    f16x8 a = *(const f16x8*)(Am + kk);
    f16x8 b0 = *(const f16x8*)(Brel0 + kk);
    f16x8 b1 = *(const f16x8*)(Brel1 + kk);
    acc0 = __builtin_amdgcn_mfma_f32_16x16x32_f16(a, b0, acc0, 0, 0, 0);
    acc1 = __builtin_amdgcn_mfma_f32_16x16x32_f16(a, b1, acc1, 0, 0, 0);
  }
  #pragma unroll
  for (int kk = 0; kk < HH; kk += 32){
    f16x8 a = *(const f16x8*)(Ax + kk);
    f16x8 b0 = *(const f16x8*)(Broot0 + kk);
    f16x8 b1 = *(const f16x8*)(Broot1 + kk);
    acc0 = __builtin_amdgcn_mfma_f32_16x16x32_f16(a, b0, acc0, 0, 0, 0);
    acc1 = __builtin_amdgcn_mfma_f32_16x16x32_f16(a, b1, acc1, 0, 0, 0);
  }
  int rbase = (lane >> 4) * 4;
  int h0 = w*32 + l15, h1 = h0 + 16;
  float bb0 = brel[h0], bb1 = brel[h1];
  float cs0 = 0.f, cs1 = 0.f;
  #pragma unroll
  for (int r = 0; r < 4; ++r){
    int row = r0 + rbase + r;
    float v0 = fmaxf(acc0[r] + bb0, 0.f);
    float v1 = fmaxf(acc1[r] + bb1, 0.f);
    xout[(size_t)row*HH + h0] = v0;
    xout[(size_t)row*HH + h1] = v1;
    xouth[(size_t)row*HH + h0] = __float2half(v0);
    xouth[(size_t)row*HH + h1] = __float2half(v1);
    cs0 += v0; cs1 += v1;
  }
  cs0 += __shfl_xor(cs0, 16); cs0 += __shfl_xor(cs0, 32);
  cs1 += __shfl_xor(cs1, 16); cs1 += __shfl_xor(cs1, 32);
  if (lane < 16){
    atomicAdd(&cmout[h0], cs0 / (float)NN);
    atomicAdd(&cmout[h1], cs1 / (float)NN);
  }
}

// dense-conv linear: mean from 4 K-quarter partials / deg; optional xout; fused column-mean.
__global__ void k_lin2(const float* __restrict__ part, const int* __restrict__ deg,
                       const float* __restrict__ xin,
                       const float* __restrict__ Wrel, const float* __restrict__ brel,
                       const float* __restrict__ Wroot, float* __restrict__ xout, int rows,
                       float* __restrict__ cmout){
  __shared__ float ms[16][HH];
  __shared__ float xs[16][HH];
  __shared__ float cmred[256];
  const float* p0 = part;
  const float* p1 = part + (size_t)KC*HH;
  const float* p2 = part + (size_t)2*KC*HH;
  const float* p3 = part + (size_t)3*KC*HH;
  int tid = threadIdx.x;
  int r0 = blockIdx.x * 16;
  for (int l = tid; l < 16*HH; l += 256){
    int r = l >> 7, c = l & 127; int gr = r0 + r;
    float mv = 0.f, xv = 0.f;
    if (gr < rows){
      size_t idx = (size_t)gr*HH + c;
      float d = fmaxf((float)deg[gr], 1.f);
      mv = ((p0[idx] + p1[idx]) + (p2[idx] + p3[idx])) / d;
      xv = xin[idx];
    }
    ms[r][c] = mv; xs[r][c] = xv;
  }
  __syncthreads();
  int h = tid & 127, hgrp = tid >> 7;
  float acc[8] = {0.f,0.f,0.f,0.f,0.f,0.f,0.f,0.f};
  for (int c = 0; c < HH; ++c){
    float wr = Wrel[h*HH + c], wo = Wroot[h*HH + c];
    #pragma unroll
    for (int r = 0; r < 8; ++r) acc[r] += ms[hgrp*8 + r][c]*wr + xs[hgrp*8 + r][c]*wo;
  }
  float bb = brel[h];
  float csum = 0.f;
  #pragma unroll
  for (int r = 0; r < 8; ++r){
    int gr = r0 + hgrp*8 + r;
    if (gr < rows){
      float val = fmaxf(acc[r] + bb, 0.f);
      if (xout) xout[(size_t)gr*HH + h] = val;
      csum += val;
    }
  }
  cmred[tid] = csum; __syncthreads();
  if (tid < 128) atomicAdd(&cmout[h], (cmred[tid] + cmred[tid + 128]) / (float)rows);
}

__global__ void k_xdot(const float* __restrict__ x2, const float* __restrict__ Watt, float* __restrict__ xdot){
  __shared__ float red[128];
  int n = blockIdx.x, t = threadIdx.x;
  float v = redSum128(red, t, x2[(size_t)n*HH + t] * Watt[HH + t]);
  if (t == 0) xdot[n] = v;
}

// per dst node v: xq max -> qdot; edge-softmax stats; x_new; wD; fused LEConv partials.
__global__ void k_pool(const float* __restrict__ x2, const int* __restrict__ rowD, const int* __restrict__ colD,
                       const float* __restrict__ xdotA, const float* __restrict__ wA2, const float* __restrict__ battp,
                       const float* __restrict__ W1, const float* __restrict__ b1,
                       const float* __restrict__ W2, const float* __restrict__ W3, const float* __restrict__ b3,
                       float* qdotA, float* mA, float* sA, float* __restrict__ xnew, float* __restrict__ wD,
                       float* aA, float* bA, float* cA){
  __shared__ float red[128];
  __shared__ float wmem[128];
  __shared__ int uc[128];
  int v = blockIdx.x, t = threadIdx.x;
  int beg = rowD[v], end = rowD[v+1];
  float batt = battp[0];
  float mx = -3.402823466e38f;
  int p = beg;
  for (; p + 4 <= end; p += 4){
    float a0 = x2[(size_t)colD[p]*HH + t];
    float a1 = x2[(size_t)colD[p+1]*HH + t];
    float a2 = x2[(size_t)colD[p+2]*HH + t];
    float a3 = x2[(size_t)colD[p+3]*HH + t];
    mx = fmaxf(fmaxf(fmaxf(fmaxf(mx, a0), a1), a2), a3);
  }
  for (; p < end; ++p) mx = fmaxf(mx, x2[(size_t)colD[p]*HH + t]);
  float qd = redSum128(red, t, mx * wA2[t]) + wA2[HH];
  float lm = -3.402823466e38f;
  for (p = beg + t; p < end; p += 128) lm = fmaxf(lm, lrelu02(qd + xdotA[colD[p]] + batt));
  float mm = redMax128(red, t, lm);
  float ls = 0.f;
  for (p = beg + t; p < end; p += 128) ls += expf(lrelu02(qd + xdotA[colD[p]] + batt) - mm);
  float ss = redSum128(red, t, ls);
  float acc = 0.f;
  for (int basep = beg; basep < end; basep += 128){
    int cnt = min(128, end - basep);
    if (t < cnt){
      int u = colD[basep + t];
      uc[t] = u;
      float w = expf(lrelu02(qd + xdotA[u] + batt) - mm) / ss;
      wmem[t] = w;
      wD[basep + t] = w;
    }
    __syncthreads();
    int i = 0;
    for (; i + 4 <= cnt; i += 4){
      float a0 = x2[(size_t)uc[i]*HH + t];
      float a1 = x2[(size_t)uc[i+1]*HH + t];
      float a2 = x2[(size_t)uc[i+2]*HH + t];
      float a3 = x2[(size_t)uc[i+3]*HH + t];
      acc += wmem[i]*a0 + wmem[i+1]*a1 + wmem[i+2]*a2 + wmem[i+3]*a3;
    }
    for (; i < cnt; ++i) acc += wmem[i] * x2[(size_t)uc[i]*HH + t];
    __syncthreads();
  }
  xnew[(size_t)v*HH + t] = acc;
  float s1 = redSum128(red, t, acc * W1[t]);
  float s2 = redSum128(red, t, acc * W2[t]);
  float s3 = redSum128(red, t, acc * W3[t]);
  if (t == 0){
    qdotA[v] = qd; mA[v] = mm; sA[v] = ss;
    aA[v] = s1 + b1[0]; bA[v] = s2; cA[v] = s3 + b3[0];
  }
}

__global__ void k_fit(const int* __restrict__ rowD, const int* __restrict__ colD,
                      const float* __restrict__ aA, const float* __restrict__ bA, const float* __restrict__ cA,
                      float* __restrict__ fitA){
  __shared__ float red[128];
  int v = blockIdx.x, t = threadIdx.x;
  int beg = rowD[v], end = rowD[v+1];
  float la = 0.f;
  for (int p = beg + t; p < end; p += 128) la += aA[colD[p]];
  float s = redSum128(red, t, la);
  if (t == 0){
    float g = s - (float)(end - beg) * bA[v] + cA[v];
    fitA[v] = 1.f / (1.f + expf(-g));
  }
}

// Exact top-K SET selection via radix-select (1 block, 1024 threads).
__global__ void k_sel(const float* __restrict__ fitA, int* perm, float* fitk, int* kcol){
  __shared__ unsigned keys[NN];
  __shared__ int hist[256];
  __shared__ int sc[1024];
  __shared__ int bc[2];
  int t = threadIdx.x;
  #pragma unroll
  for (int r = 0; r < 4; ++r){
    int i = t + r*1024;
    unsigned b = __float_as_uint(fitA[i]);
    keys[i] = (b & 0x80000000u) ? ~b : (b ^ 0x80000000u);
  }
  __syncthreads();
  unsigned prefix = 0;
  int kneed = KC;
  #pragma unroll
  for (int round = 0; round < 4; ++round){
    int shift = 24 - round*8;
    unsigned pmask = (round == 0) ? 0u : (0xFFFFFFFFu << (shift + 8));
    if (t < 256) hist[t] = 0;
    __syncthreads();
    #pragma unroll
    for (int r = 0; r < 4; ++r){
      unsigned kv = keys[t + r*1024];
      if ((kv & pmask) == prefix)
        atomicAdd(&hist[(kv >> shift) & 0xFF], 1);
    }
    __syncthreads();
    if (t == 0){
      int acc = 0, chosen = 0, rem = kneed;
      for (int bkt = 255; bkt >= 0; --bkt){
        int c = hist[bkt];
        if (acc + c >= kneed){ chosen = bkt; rem = kneed - acc; break; }
        acc += c;
      }
      bc[0] = chosen; bc[1] = rem;
    }
    __syncthreads();
    prefix |= ((unsigned)bc[0]) << shift;
    kneed = bc[1];
    __syncthreads();
  }
  unsigned T = prefix;
  int need_eq = kneed;
  int cnt[4]; int tot = 0;
  #pragma unroll
  for (int r = 0; r < 4; ++r){
    unsigned kv = keys[t*4 + r];
    int g = (kv > T) ? 1 : 0;
    int e = (kv == T) ? 1 : 0;
    cnt[r] = (g << 16) | e;
    tot += cnt[r];
  }
  sc[t] = tot; __syncthreads();
  for (int offs = 1; offs < 1024; offs <<= 1){
    int v = (t >= offs) ? sc[t - offs] : 0;
    __syncthreads();
    sc[t] += v;
    __syncthreads();
  }
  int gtot = sc[1023] >> 16;
  int run = sc[t] - tot;
  #pragma unroll
  for (int r = 0; r < 4; ++r){
    int i = t*4 + r;
    int g = cnt[r] >> 16, e = cnt[r] & 0xFFFF;
    int gpos = run >> 16, epos = run & 0xFFFF;
    int pos = -1;
    if (g) pos = gpos;
    else if (e && epos < need_eq) pos = gtot + epos;
    if (pos >= 0){ perm[pos] = i; fitk[pos] = fitA[i]; kcol[i] = pos; }
    else kcol[i] = -1;
    run += cnt[r];
  }
}

// fused: xp[j,:] = xnew[perm[j],:]*fitk[j]  AND  Xt[h][j] = f16(xp[j][h])
__global__ void k_xpt(const float* __restrict__ xnew, const int* __restrict__ perm,
                      const float* __restrict__ fitk, float* __restrict__ xp,
                      __half* __restrict__ Xt){
  __shared__ float T2[64][129];
  int t = threadIdx.x;
  int j0 = blockIdx.x * 64;
  for (int l = t; l < 64*32; l += 256){
    int jl = l >> 5, hg = (l & 31) * 4;
    int j = j0 + jl;
    float4 v = make_float4(0.f, 0.f, 0.f, 0.f);
    if (j < KC){
      float f = fitk[j];
      const float* src = xnew + (size_t)perm[j]*HH + hg;
      v.x = src[0]*f; v.y = src[1]*f; v.z = src[2]*f; v.w = src[3]*f;
      *(float4*)(xp + (size_t)j*HH + hg) = v;
    }
    T2[jl][hg] = v.x; T2[jl][hg+1] = v.y; T2[jl][hg+2] = v.z; T2[jl][hg+3] = v.w;
  }
  __syncthreads();
  for (int idx = t; idx < 128*64; idx += 256){
    int h = idx >> 6, jl = idx & 63;
    Xt[(size_t)h*A2P + j0 + jl] = __float2half(T2[jl][h]);
  }
}

// src-ordered packed (kcol, w) for k_U; dst-ordered byte-offset + f16 weight for k_A2B
__global__ void k_wS(const int* __restrict__ mapSD, const int* __restrict__ dstS,
                     const int* __restrict__ kcol, const float* __restrict__ wD,
                     const int* __restrict__ colD,
                     int2* __restrict__ kwS, unsigned* __restrict__ offsD,
                     __half* __restrict__ wHD){
  int q = blockIdx.x * blockDim.x + threadIdx.x;
  if (q >= E2) return;
  float w = wD[mapSD[q]];
  int k = kcol[dstS[q]];
  kwS[q] = make_int2(k, __float_as_int(w));
  offsD[q] = (unsigned)colD[q] * (UP*2);
  wHD[q] = __float2half(wD[q]);
}

// U[n,:] = (A @ S)[n,:]. Flattened 2-hop edge list per block (full 256-thread utilization).
__global__ void k_U(const int* __restrict__ rowS, const int* __restrict__ dstS,
                    const int2* __restrict__ kwS, __half* __restrict__ U){
  __shared__ float acc[UP];   // 14 KB
  __shared__ int pref[129];
  __shared__ int nbase[128];
  int t = threadIdx.x, n = blockIdx.x;
  for (int i = t; i < UP; i += 256) acc[i] = 0.f;
  int b = rowS[n], e = rowS[n+1];
  __syncthreads();
  for (int cb = b; cb < e; cb += 128){
    int cnt = min(128, e - cb);
    if (t < cnt){
      int j = dstS[cb + t];
      int b2 = rowS[j];
      nbase[t] = b2;
      pref[t+1] = rowS[j+1] - b2;
    }
    if (t == 0) pref[0] = 0;
    __syncthreads();
    if (t == 0){
      for (int i = 0; i < cnt; ++i) pref[i+1] += pref[i];
    }
    __syncthreads();
    int total = pref[cnt];
    for (int idx = t; idx < total; idx += 256){
      int lo = 0, hi = cnt - 1;
      while (lo < hi){
        int mid = (lo + hi + 1) >> 1;
        if (pref[mid] <= idx) lo = mid; else hi = mid - 1;
      }
      int q = nbase[lo] + (idx - pref[lo]);
      int2 kw = kwS[q];
      if (kw.x >= 0) atomicAdd(&acc[kw.x], __int_as_float(kw.y));
    }
    __syncthreads();
  }
  __half2* Ur = (__half2*)(U + (size_t)n * UP);
  for (int i = t; i < UP/2; i += 256)
    Ur[i] = __halves2half2(__float2half(acc[2*i]), __float2half(acc[2*i+1]));
}

// A2[k1, cc*448 .. +447] (single-row, 8-deep ILP, row-major coalesced writes).
__global__ void k_A2B(const int* __restrict__ rowD,
                      const unsigned* __restrict__ offsD, const __half* __restrict__ wHDh,
                      const int* __restrict__ perm,
                      const __half* __restrict__ Uh, __half* __restrict__ A2,
                      int* __restrict__ deg){
  int cc = blockIdx.x & 7;
  int rt = blockIdx.x >> 3;
  int t = threadIdx.x;
  int w = t >> 6, lane = t & 63;
  int k1 = rt*4 + w;
  if (k1 >= KC) return;
  bool act = lane < 56;
  unsigned laneoff = (unsigned)(cc*448*2 + lane*16);
  const char* Ub = (const char*)Uh;
  const _Float16* wHD = (const _Float16*)wHDh;

  f16x8 accA = (f16x8)(_Float16)0, accB = (f16x8)(_Float16)0;
  f16x8 accC = (f16x8)(_Float16)0, accD = (f16x8)(_Float16)0;
  int v1 = perm[k1];
  int p = rowD[v1], end = rowD[v1+1];

  int pre = (8 - (p & 7)) & 7;
  if (pre > end - p) pre = end - p;
  for (int z = 0; z < pre; ++z, ++p){
    unsigned off = offsD[p];
    _Float16 w0 = wHD[p];
    if (act){
      f16x8 u = *(const f16x8*)(Ub + (size_t)(off + laneoff));
      accA += u * w0;
    }
  }
  for (; p + 8 <= end; p += 8){
    uint4 oA = *(const uint4*)(offsD + p);
    uint4 oB = *(const uint4*)(offsD + p + 4);
    f16x8 wv = *(const f16x8*)(wHD + p);
    if (act){
      f16x8 u0 = *(const f16x8*)(Ub + (size_t)(oA.x + laneoff));
      f16x8 u1 = *(const f16x8*)(Ub + (size_t)(oA.y + laneoff));
      f16x8 u2 = *(const f16x8*)(Ub + (size_t)(oA.z + laneoff));
      f16x8 u3 = *(const f16x8*)(Ub + (size_t)(oA.w + laneoff));
      f16x8 u4 = *(const f16x8*)(Ub + (size_t)(oB.x + laneoff));
      f16x8 u5 = *(const f16x8*)(Ub + (size_t)(oB.y + laneoff));
      f16x8 u6 = *(const f16x8*)(Ub + (size_t)(oB.z + laneoff));
      f16x8 u7 = *(const f16x8*)(Ub + (size_t)(oB.w + laneoff));
      accA += u0 * wv[0];
      accB += u1 * wv[1];
      accC += u2 * wv[2];
      accD += u3 * wv[3];
      accA += u4 * wv[4];
      accB += u5 * wv[5];
      accC += u6 * wv[6];
      accD += u7 * wv[7];
    }
  }
  for (; p < end; ++p){
    unsigned off = offsD[p];
    _Float16 w0 = wHD[p];
    if (act){
      f16x8 u = *(const f16x8*)(Ub + (size_t)(off + laneoff));
      accB += u * w0;
    }
  }
  f16x8 acc = (accA + accB) + (accC + accD);

  int col0 = cc*448 + lane * 8;
  f16x8 o = (f16x8)(_Float16)0;
  int c = 0;
  if (act){
    #pragma unroll
    for (int e = 0; e < 8; ++e){
      int col = col0 + e;
      _Float16 hv = (col == k1 || col >= KC) ? (_Float16)0 : acc[e];
      o[e] = hv;
      c += (hv != (_Float16)0) ? 1 : 0;
    }
  }
  #pragma unroll
  for (int s = 32; s > 0; s >>= 1) c += __shfl_down(c, s);
  if (lane == 0) atomicAdd(&deg[k1], c);
  if (act && col0 + 8 <= A2P)
    *(f16x8*)(A2 + (size_t)k1 * A2P + col0) = o;
}

// LDS-tiled transpose: A2T[i][j] = A2[j][i]; rows j >= KC read as zero.
__global__ void k_tr(const __half* __restrict__ A2, __half* __restrict__ A2T){
  __shared__ float tile[64][65];
  int t = threadIdx.x;
  int i0 = blockIdx.x * 64, j0 = blockIdx.y * 64;
  int sl = t & 7;
  #pragma unroll
  for (int p = 0; p < 2; ++p){
    int jl = (t >> 3) + p*32;
    int j = j0 + jl;
    f16x8 v;
    if (j < KC) v = *(const f16x8*)(A2 + (size_t)j*A2P + i0 + sl*8);
    else v = (f16x8)(_Float16)0;
    #pragma unroll
    for (int e = 0; e < 8; ++e) tile[jl][sl*8 + e] = (float)v[e];
  }
  __syncthreads();
  #pragma unroll
  for (int p = 0; p < 2; ++p){
    int il = (t >> 3) + p*32;
    int i = i0 + il;
    f16x8 o;
    #pragma unroll
    for (int e = 0; e < 8; ++e) o[e] = (_Float16)tile[sl*8 + e][il];
    *(f16x8*)(A2T + (size_t)i*A2P + j0 + sl*8) = o;
  }
}

// Xt[h][j] = (f16) X[j][h], zero-padded for j >= KC.
__global__ void k_xt(const float* __restrict__ X, __half* __restrict__ Xt){
  __shared__ float T2[64][129];
  int t = threadIdx.x;
  int j0 = blockIdx.x * 64;
  for (int l = t; l < 64*32; l += 256){
    int jl = l >> 5, hg = (l & 31) * 4;
    int j = j0 + jl;
    float4 v = make_float4(0.f, 0.f, 0.f, 0.f);
    if (j < KC) v = *(const float4*)(X + (size_t)j*HH + hg);
    T2[jl][hg] = v.x; T2[jl][hg+1] = v.y; T2[jl][hg+2] = v.z; T2[jl][hg+3] = v.w;
  }
  __syncthreads();
  for (int idx = t; idx < 128*64; idx += 256){
    int h = idx >> 6, jl = idx & 63;
    Xt[(size_t)h*A2P + j0 + jl] = __float2half(T2[jl][h]);
  }
}

// MFMA dagg: 32i x 128h per block, K-split 4, atomic-free.
__global__ void k_mm(const __half* __restrict__ A2Th, const __half* __restrict__ Xth,
                     float* __restrict__ part){
  const _Float16* A2T = (const _Float16*)A2Th;
  const _Float16* Xt  = (const _Float16*)Xth;
  int t = threadIdx.x;
  int lane = t & 63, w = t >> 6;
  int i0 = (blockIdx.x >> 2) * 32;
  int kq = blockIdx.x & 3;
  int kbeg = kq * KQ;
  float* po = part + (size_t)kq * KC * HH;
  int l15 = lane & 15, lk = (lane >> 4) * 8;
  const _Float16* Ar0 = A2T + (size_t)(i0 + l15) * A2P + lk + kbeg;
  const _Float16* Ar1 = Ar0 + (size_t)16 * A2P;
  const _Float16* B0 = Xt + (size_t)(w*32 + l15) * A2P + lk + kbeg;
  const _Float16* B1 = B0 + (size_t)16 * A2P;
  f32x4 acc00 = (f32x4)0.f, acc01 = (f32x4)0.f;
  f32x4 acc10 = (f32x4)0.f, acc11 = (f32x4)0.f;
  for (int kk = 0; kk < KQ; kk += 64){
    f16x8 a00 = *(const f16x8*)(Ar0 + kk);
    f16x8 a01 = *(const f16x8*)(Ar0 + kk + 32);
    f16x8 a10 = *(const f16x8*)(Ar1 + kk);
    f16x8 a11 = *(const f16x8*)(Ar1 + kk + 32);
    f16x8 b00 = *(const f16x8*)(B0 + kk);
    f16x8 b01 = *(const f16x8*)(B1 + kk);
    f16x8 b10 = *(const f16x8*)(B0 + kk + 32);
    f16x8 b11 = *(const f16x8*)(B1 + kk + 32);
    acc00 = __builtin_amdgcn_mfma_f32_16x16x32_f16(a00, b00, acc00, 0, 0, 0);
    acc01 = __builtin_amdgcn_mfma_f32_16x16x32_f16(a00, b01, acc01, 0, 0, 0);
    acc10 = __builtin_amdgcn_mfma_f32_16x16x32_f16(a10, b00, acc10, 0, 0, 0);
    acc11 = __builtin_amdgcn_mfma_f32_16x16x32_f16(a10, b01, acc11, 0, 0, 0);
    acc00 = __builtin_amdgcn_mfma_f32_16x16x32_f16(a01, b10, acc00, 0, 0, 0);
    acc01 = __builtin_amdgcn_mfma_f32_16x16x32_f16(a01, b11, acc01, 0, 0, 0);
    acc10 = __builtin_amdgcn_mfma_f32_16x16x32_f16(a11, b10, acc10, 0, 0, 0);
    acc11 = __builtin_amdgcn_mfma_f32_16x16x32_f16(a11, b11, acc11, 0, 0, 0);
  }
  int rbase = (lane >> 4) * 4;
  #pragma unroll
  for (int r = 0; r < 4; ++r){
    int ia = i0 + rbase + r;
    int ib = ia + 16;
    if (ia < KC){
      po[(size_t)ia*HH + w*32 + l15] = acc00[r];
      po[(size_t)ia*HH + w*32 + 16 + l15] = acc01[r];
    }
    if (ib < KC){
      po[(size_t)ib*HH + w*32 + l15] = acc10[r];
      po[(size_t)ib*HH + w*32 + 16 + l15] = acc11[r];
    }
  }
}

} // namespace

extern "C" void kernel_launch(void* const* d_in, const int* in_sizes, int n_in,
                              void* d_out, int out_size, void* d_ws, size_t ws_size,
                              hipStream_t stream){
  (void)in_sizes; (void)n_in; (void)out_size; (void)ws_size;
  const float* x      = (const float*)d_in[0];
  const int*   ei     = (const int*)d_in[1];
  const float* c0Wrel = (const float*)d_in[2];
  const float* c0brel = (const float*)d_in[3];
  const float* c0Wroot= (const float*)d_in[4];
  const float* c1Wrel = (const float*)d_in[5];
  const float* c1brel = (const float*)d_in[6];
  const float* c1Wroot= (const float*)d_in[7];
  const float* c2Wrel = (const float*)d_in[8];
  const float* c2brel = (const float*)d_in[9];
  const float* c2Wroot= (const float*)d_in[10];
  const float* c3Wrel = (const float*)d_in[11];
  const float* c3brel = (const float*)d_in[12];
  const float* c3Wroot= (const float*)d_in[13];
  const float* Wlin   = (const float*)d_in[14];
  const float* blin   = (const float*)d_in[15];
  const float* Watt   = (const float*)d_in[16];
  const float* batt   = (const float*)d_in[17];
  const float* W1     = (const float*)d_in[18];
  const float* b1     = (const float*)d_in[19];
  const float* W2     = (const float*)d_in[20];
  const float* W3     = (const float*)d_in[21];
  const float* b3     = (const float*)d_in[22];
  float* out = (float*)d_out;

  char* base = (char*)d_ws;
  size_t off = 0;
  auto carve = [&](size_t bytes) -> void* {
    void* p = base + off;
    off += (bytes + 255) & ~(size_t)255;
    return p;
  };
  float* x1    = (float*)carve((size_t)NN*HH*4);
  float* x2b   = (float*)carve((size_t)NN*HH*4);
  float* xnew  = (float*)carve((size_t)NN*HH*4);
  float* xp    = (float*)carve((size_t)KC*HH*4);
  float* x3    = (float*)carve((size_t)KC*HH*4);
  float* part  = (float*)carve((size_t)4*KC*HH*4);   // 4 K-quarter partials
  __half* A2   = (__half*)carve((size_t)KC*A2P*2);   // ~22 MB
  __half* U    = (__half*)carve((size_t)NN*UP*2);    // ~29 MB; dead after k_A2B -> reused as A2T
  __half* A2T  = U;
  __half* Xt   = (__half*)carve((size_t)HH*A2P*2);
  __half* xh   = (__half*)carve((size_t)NN*HH*2);
  __half* x1h  = (__half*)carve((size_t)NN*HH*2);
  __half* x2bh = (__half*)carve((size_t)NN*HH*2);
  __half* mbh  = (__half*)carve((size_t)NN*HH*2);
  __half* WH   = (__half*)carve((size_t)4*HH*HH*2);
  float* xdot  = (float*)carve(NN*4);
  float* qdot  = (float*)carve(NN*4);
  float* mmaxA = (float*)carve(NN*4);
  float* ssumA = (float*)carve(NN*4);
  float* aA    = (float*)carve(NN*4);
  float* bA    = (float*)carve(NN*4);
  float* cA    = (float*)carve(NN*4);
  float* fitA  = (float*)carve(NN*4);
  float* fitk  = (float*)carve(KC*4);
  float* wA2   = (float*)carve((HH+1)*4);
  float* wD    = (float*)carve((size_t)E2*4);
  int* rowD = (int*)carve((NN+1)*4);
  int* rowS = (int*)carve((NN+1)*4);
  int* cntD = (int*)carve(NN*4);
  int* cntS = (int*)carve(NN*4);
  int* curD = (int*)carve(NN*4);
  int* curS = (int*)carve(NN*4);
  int* colD = (int*)carve((size_t)E2*4);
  int* dstS = (int*)carve((size_t)E2*4);
  int* mapSD= (int*)carve((size_t)E2*4);
  int2* kwS = (int2*)carve((size_t)E2*8);
  unsigned* offsD = (unsigned*)carve((size_t)E2*4);
  __half* wHD = (__half*)carve((size_t)E2*2);
  int* perm = (int*)carve(KC*4);
  int* kcol = (int*)carve(NN*4);
  int* deg3 = (int*)carve(KC*4);

  k_zero_init<<<NN/256, 256, 0, stream>>>(cntD, cntS, deg3, out);
  k_count<<<(E2+255)/256, 256, 0, stream>>>(ei, cntD, cntS);
  k_scan<<<1, 1024, 0, stream>>>(cntD, cntS, rowD, rowS, curD, curS);
  k_scatter<<<(E2+255)/256, 256, 0, stream>>>(ei, curD, curS, colD, dstS, mapSD);
  k_prep<<<2048 + 256 + 1, 256, 0, stream>>>(x, c0Wrel, c0Wroot, c1Wrel, c1Wroot,
                                             Wlin, blin, Watt, xh, WH, wA2);

  // conv0 (MFMA linear; colmean fused)
  k_edge_meanH<<<NN, 128, 0, stream>>>(xh, rowD, colD, mbh);
  k_linM<<<NN/16, 256, 0, stream>>>(mbh, xh, WH, 0, c0brel, x1, x1h, out + 0);

  // conv1
  k_edge_meanH<<<NN, 128, 0, stream>>>(x1h, rowD, colD, mbh);
  k_linM<<<NN/16, 256, 0, stream>>>(mbh, x1h, WH, 32768, c1brel, x2b, x2bh, out + 128);

  // ASAP pool
  k_xdot<<<NN, 128, 0, stream>>>(x2b, Watt, xdot);
  k_pool<<<NN, 128, 0, stream>>>(x2b, rowD, colD, xdot, wA2, batt,
                                 W1, b1, W2, W3, b3,
                                 qdot, mmaxA, ssumA, xnew, wD, aA, bA, cA);
  k_fit<<<NN, 128, 0, stream>>>(rowD, colD, aA, bA, cA, fitA);
  k_sel<<<1, 1024, 0, stream>>>(fitA, perm, fitk, kcol);
  k_wS<<<(E2+255)/256, 256, 0, stream>>>(mapSD, dstS, kcol, wD, colD, kwS, offsD, wHD);
  k_U<<<NN, 256, 0, stream>>>(rowS, dstS, kwS, U);
  k_A2B<<<A2B_RT*8, 256, 0, stream>>>(rowD, offsD, wHD, perm, U, A2, deg3);

  // transpose A2 -> A2T (U is dead now; A2T aliases it)
  k_tr<<<dim3(A2P/64, A2P/64), 256, 0, stream>>>(A2, A2T);

  // conv2 (MFMA K-split 4; partial-sum + deg-mean + colmean fused into k_lin2)
  k_xpt<<<A2P/64, 256, 0, stream>>>(xnew, perm, fitk, xp, Xt);
  k_mm<<<(A2P/32)*4, 256, 0, stream>>>(A2T, Xt, part);
  k_lin2<<<(KC+15)/16, 256, 0, stream>>>(part, deg3, xp,
                                         c2Wrel, c2brel, c2Wroot, x3, KC, out + 256);

  // conv3 (x4 never materialized; only its column-mean is needed)
  k_xt<<<A2P/64, 256, 0, stream>>>(x3, Xt);
  k_mm<<<(A2P/32)*4, 256, 0, stream>>>(A2T, Xt, part);
  k_lin2<<<(KC+15)/16, 256, 0, stream>>>(part, deg3, x3,
                                         c3Wrel, c3brel, c3Wroot, nullptr, KC, out + 384);
}